// Round 4
// baseline (27838.187 us; speedup 1.0000x reference)
//
#include <hip/hip_runtime.h>
#include <math.h>

#define LAYERS 12
#define EE 1024
#define GG 2730
#define VV 16416
#define EPS 1e-6f
#define NBLK 1024
#define NGRP 32
#define GRPSZ (NBLK/NGRP)

// ---- workspace layout (float offsets) ----
#define OFF_EK 0
#define OFF_EV 1572864
#define OFF_DS 3145728
#define NSLOT 37
#define OFF_ACC (OFF_DS + NSLOT*2048)
#define ACC_STRIDE 28672
#define AQ 0
#define AK 2048
#define AV 4096
#define AY 6144
#define AQC 8192
#define AY2 10240
#define AA 12288
#define AB2 17748
#define ACC_TOTAL (LAYERS*ACC_STRIDE)
#define OFF_BAR (OFF_ACC + ACC_TOTAL)
#define ZERO_FLOATS (NSLOT*2048 + ACC_TOTAL + 4096)

#define KVL 524288   // floats per layer per cache (2 batches x 256 x 1024)
#define KVB 262144   // floats per batch

struct MegaP {
  const float* enc; const float* keys_in; const float* values_in;
  const int* maski; const int* pt; const int* ti;
  const float* tok; const float* pos; const float* ln_s; const float* ln_b;
  const float* final_b; const float* lm_w;
  const float* pre_sa_b; const float* saq; const float* sak; const float* sav;
  const float* sao; const float* sas; const float* sab;
  const float* pre_ca_b; const float* caq; const float* cao;
  const float* cas; const float* cab;
  const float* g0b; const float* f0; const float* f1; const float* g1b; const float* f2;
  float* logits; float* keys_out; float* values_out; float* ws;
};

__device__ __forceinline__ void red4(float* sm, float& a, float& b, float& c, float& d){
  #pragma unroll
  for(int o=32;o;o>>=1){ a+=__shfl_down(a,o); b+=__shfl_down(b,o); c+=__shfl_down(c,o); d+=__shfl_down(d,o); }
  int w=threadIdx.x>>6, l=threadIdx.x&63;
  __syncthreads();
  if(l==0){ sm[w]=a; sm[4+w]=b; sm[8+w]=c; sm[12+w]=d; }
  __syncthreads();
  a=sm[0]+sm[1]+sm[2]+sm[3]; b=sm[4]+sm[5]+sm[6]+sm[7];
  c=sm[8]+sm[9]+sm[10]+sm[11]; d=sm[12]+sm[13]+sm[14]+sm[15];
}

__device__ __forceinline__ void ln_stats_g(const float* v, int K, float* sm,
    float& mu0, float& rs0, float& mu1, float& rs1){
  float s0=0,q0=0,s1=0,q1=0;
  for(int i=threadIdx.x;i<K;i+=256){ float a=v[i], b=v[K+i]; s0+=a;q0+=a*a;s1+=b;q1+=b*b; }
  red4(sm,s0,q0,s1,q1);
  mu0=s0/K; mu1=s1/K;
  rs0=rsqrtf(fmaxf(q0/K-mu0*mu0,0.f)+EPS);
  rs1=rsqrtf(fmaxf(q1/K-mu1*mu1,0.f)+EPS);
}

__device__ __forceinline__ void ln_stats_l(float (*Ds)[1024], float* sm,
    float& mu0, float& rs0, float& mu1, float& rs1){
  float s0=0,q0=0,s1=0,q1=0;
  for(int i=threadIdx.x;i<EE;i+=256){ float a=Ds[0][i], b=Ds[1][i]; s0+=a;q0+=a*a;s1+=b;q1+=b*b; }
  red4(sm,s0,q0,s1,q1);
  mu0=s0/EE; mu1=s1/EE;
  rs0=rsqrtf(fmaxf(q0/EE-mu0*mu0,0.f)+EPS);
  rs1=rsqrtf(fmaxf(q1/EE-mu1*mu1,0.f)+EPS);
}

// ds3 = dsi + LN(AY)*sas+sab + LN(AY2)*cas+cab  -> Ds
__device__ __forceinline__ void build_ds3(const float* dsi, const float* accL,
    const float* sasl, const float* sabl, const float* casl, const float* cabl,
    float (*Ds)[1024], float* sm){
  float mu0,rs0,mu1,rs1;
  ln_stats_g(accL+AY, EE, sm, mu0,rs0,mu1,rs1);
  for(int i=threadIdx.x;i<EE;i+=256){ float sc=sasl[i], bi=sabl[i];
    Ds[0][i]=dsi[i]    + (accL[AY+i]-mu0)*rs0*sc + bi;
    Ds[1][i]=dsi[EE+i] + (accL[AY+EE+i]-mu1)*rs1*sc + bi; }
  ln_stats_g(accL+AY2, EE, sm, mu0,rs0,mu1,rs1);
  for(int i=threadIdx.x;i<EE;i+=256){ float sc=casl[i], bi=cabl[i];
    Ds[0][i] += (accL[AY2+i]-mu0)*rs0*sc + bi;
    Ds[1][i] += (accL[AY2+EE+i]-mu1)*rs1*sc + bi; }
}

// Low-contention tree barrier, monotonic counters (no resets).
// bar layout (ints): grp arrival at grp*32 ; master at 1024 ; grp gen line at 1056+grp*32.
__device__ __forceinline__ void gridbar(int* bar, int g){
  __syncthreads();
  if (threadIdx.x==0){
    __threadfence();
    int grp = blockIdx.x & (NGRP-1);
    int v = __hip_atomic_fetch_add(&bar[grp*32], 1, __ATOMIC_ACQ_REL, __HIP_MEMORY_SCOPE_AGENT);
    if (v == (g+1)*GRPSZ - 1){
      int m = __hip_atomic_fetch_add(&bar[1024], 1, __ATOMIC_ACQ_REL, __HIP_MEMORY_SCOPE_AGENT);
      if (m == (g+1)*NGRP - 1){
        #pragma unroll 4
        for (int q=0;q<NGRP;q++)
          __hip_atomic_store(&bar[1056+q*32], g+1, __ATOMIC_RELEASE, __HIP_MEMORY_SCOPE_AGENT);
      }
    }
    int it=0;
    while (__hip_atomic_load(&bar[1056+grp*32], __ATOMIC_ACQUIRE, __HIP_MEMORY_SCOPE_AGENT) <= g){
      __builtin_amdgcn_s_sleep(16);
      if (++it > (1<<16)) break;   // safety valve: fail absmax, don't hang
    }
    __threadfence();
  }
  __syncthreads();
}

// LLC prefetch helper: stream [n4 float4] starting at src across nb blocks.
__device__ __forceinline__ void prefetch4(const float4* src, size_t n4, int pb, int nb){
  float s=0;
  for (size_t i = (size_t)pb*256 + threadIdx.x; i < n4; i += (size_t)nb*256){
    float4 v = src[i]; s += v.x+v.y+v.z+v.w;
  }
  asm volatile("" :: "v"(s));
}

// batched ek/ev precompute: out[l][row][:] = enc[row][:] @ W[l]
__global__ __launch_bounds__(256)
void k_ekev(const float* __restrict__ enc, const float* __restrict__ ckw,
            const float* __restrict__ cvw, float* __restrict__ ws){
  int lp = blockIdx.y; int l = lp>>1, proj = lp&1;
  const float* Wt = (proj? cvw : ckw) + (size_t)l*EE*EE;
  float* out = ws + (proj? OFF_EV : OFF_EK) + (size_t)l*128*EE;
  int c0 = blockIdx.x*32;
  __shared__ float As[128][33];
  __shared__ float Bs[32][33];
  int t=threadIdx.x, tx=t&7, ty=t>>3;
  float acc[4][4];
  #pragma unroll
  for(int i=0;i<4;i++){ acc[i][0]=0;acc[i][1]=0;acc[i][2]=0;acc[i][3]=0; }
  for (int k0=0;k0<EE;k0+=32){
    for (int i=t;i<128*32;i+=256){ int r=i>>5, k=i&31; As[r][k] = enc[(size_t)r*EE + k0+k]; }
    for (int i=t;i<32*32;i+=256){ int k=i>>5, c=i&31; Bs[k][c] = Wt[(size_t)(k0+k)*EE + c0+c]; }
    __syncthreads();
    #pragma unroll 8
    for (int k=0;k<32;k++){
      float b0=Bs[k][tx*4+0], b1=Bs[k][tx*4+1], b2=Bs[k][tx*4+2], b3=Bs[k][tx*4+3];
      #pragma unroll
      for (int rr=0;rr<4;rr++){
        float av = As[ty+32*rr][k];
        acc[rr][0]+=av*b0; acc[rr][1]+=av*b1; acc[rr][2]+=av*b2; acc[rr][3]+=av*b3;
      }
    }
    __syncthreads();
  }
  #pragma unroll
  for (int rr=0;rr<4;rr++)
    #pragma unroll
    for (int j=0;j<4;j++)
      out[(size_t)(ty+32*rr)*EE + c0 + tx*4+j] = acc[rr][j];
}

__global__ __launch_bounds__(256, 4)
void k_mega(MegaP p){
  __shared__ float Xs[2][2736];
  __shared__ float Ds[2][1024];
  __shared__ float att[2][256];
  __shared__ float sm[16];

  const int t = threadIdx.x;
  const int bkid = blockIdx.x;
  int* bar = (int*)(p.ws + OFF_BAR);
  const int tiv = p.ti[0];
  int g = 0;

  // ---- prelude (block 0): ds0 = LN(tok[pt]+pos[ti], s, b), atomic into zeroed slot0
  if (bkid==0){
    int ptv = p.pt[0];
    float s0=0,q0=0,d1=0,d2=0;
    for(int i=t;i<EE;i+=256){ float v=p.tok[(size_t)ptv*EE+i]+p.pos[(size_t)tiv*EE+i]; Xs[0][i]=v; s0+=v; q0+=v*v; }
    red4(sm,s0,q0,d1,d2);
    float mu=s0/EE, rs=rsqrtf(fmaxf(q0/EE-mu*mu,0.f)+EPS);
    float* ds0 = p.ws + OFF_DS;
    for(int i=t;i<EE;i+=256){ float y=(Xs[0][i]-mu)*rs*p.ln_s[i]+p.ln_b[i]; atomicAdd(&ds0[i],y); atomicAdd(&ds0[EE+i],y); }
  } else if (bkid >= 256){
    // prefetch layer-0 saq/sak/sav into LLC while prelude runs
    prefetch4((const float4*)p.saq, (size_t)EE*EE/4, bkid-256, 768);
  }
  gridbar(bar, g++);

  for (int l=0;l<LAYERS;l++){
    float* accL = p.ws + OFF_ACC + (size_t)l*ACC_STRIDE;
    const float* dsi = p.ws + OFF_DS + (size_t)(3*l)*2048;
    float* ds4 = p.ws + OFF_DS + (size_t)(3*l+3)*2048;
    const size_t lE2 = (size_t)l*EE*EE;
    const size_t lE  = (size_t)l*EE;
    const size_t lEG = (size_t)l*EE*GG;
    const size_t lGE = (size_t)l*GG*EE;
    const size_t lG  = (size_t)l*GG;

    // ===== stage A: x=LN(dsi)+pre_sa_b ; q,k,v GEMV (768 blocks) + KV copy (256 blocks)
    if (bkid < 768){
      float mu0,rs0,mu1,rs1;
      ln_stats_g(dsi, EE, sm, mu0,rs0,mu1,rs1);
      for(int i=t;i<EE;i+=256){ float bi=p.pre_sa_b[lE+i];
        Xs[0][i]=(dsi[i]-mu0)*rs0+bi; Xs[1][i]=(dsi[EE+i]-mu1)*rs1+bi; }
      __syncthreads();
      int cg = bkid % 12, ks = bkid / 12;     // 12 cg x 64 ks, CH=16
      int c = cg*256 + t;
      int sel = c >> 10, cc = c & 1023;
      const float* W = (sel==0? p.saq : sel==1? p.sak : p.sav) + lE2;
      float* O = accL + (sel==0? AQ : sel==1? AK : AV);
      int k0 = ks*16;
      float a0=0,a1=0;
      const float* wp = W + (size_t)k0*EE + cc;
      #pragma unroll 4
      for(int k=0;k<16;k++){ float w=*wp; wp+=EE; a0+=Xs[0][k0+k]*w; a1+=Xs[1][k0+k]*w; }
      atomicAdd(&O[cc],a0); atomicAdd(&O[EE+cc],a1);
    } else {
      int bi = bkid - 768;                     // 256 copy blocks: this layer's KV slice
      #pragma unroll
      for(int j=0;j<4;j++){
        int idx4 = bi*1024 + j*256 + t;        // 262144 float4 per layer
        int e4 = idx4 & 255, tt=(idx4>>8)&255, bb2=(idx4>>16)&1, kv=(idx4>>17)&1;
        if (tt==tiv) continue;                 // row ti written by stage C
        size_t off = (size_t)l*KVL + (size_t)bb2*KVB + (size_t)tt*EE + (size_t)e4*4;
        float4 v = *(const float4*)((kv? p.values_in : p.keys_in) + off);
        *(float4*)((kv? p.values_out : p.keys_out) + off) = v;
      }
    }
    gridbar(bar, g++);

    // ===== stage C: self-attention (inline) + y = attn @ sao  (256 blocks)
    if (bkid < 256){
      int cg=bkid&3, h=(bkid>>2)&15, sub=(bkid>>6)&3, hoff=h*64;
      if (t < 128){ int bb2=t>>6, c2=t&63; Ds[bb2][c2] = accL[AQ + bb2*EE + hoff + c2]*0.125f; }
      __syncthreads();
      for(int bb2=0;bb2<2;bb2++)
        for(int tt=t; tt<=tiv; tt+=256){
          const float* kr = (tt<tiv) ? (p.keys_in + (size_t)l*KVL + (size_t)bb2*KVB + (size_t)tt*EE + hoff)
                                     : (accL + AK + bb2*EE + hoff);
          float d=0;
          #pragma unroll
          for(int c2=0;c2<64;c2++) d += Ds[bb2][c2]*kr[c2];
          att[bb2][tt] = d;
        }
      __syncthreads();
      int wv=t>>6, l2=t&63;
      if (wv<2){
        float m=-3.4e38f;
        for(int tt=l2; tt<=tiv; tt+=64) m=fmaxf(m, att[wv][tt]);
        #pragma unroll
        for(int o=32;o;o>>=1) m=fmaxf(m,__shfl_xor(m,o));
        float s=0;
        for(int tt=l2; tt<=tiv; tt+=64){ float e=__expf(att[wv][tt]-m); att[wv][tt]=e; s+=e; }
        #pragma unroll
        for(int o=32;o;o>>=1) s+=__shfl_xor(s,o);
        if(l2==0) sm[8+wv]=1.f/s;
      }
      __syncthreads();
      {
        int bb2=t>>7, j=(t>>3)&15, part=t&7, colh=sub*16+j;
        float v=0;
        for(int tt=part; tt<=tiv; tt+=8){
          float vv = (tt<tiv)? p.values_in[(size_t)l*KVL + (size_t)bb2*KVB + (size_t)tt*EE + hoff + colh]
                             : accL[AV + bb2*EE + hoff + colh];
          v += att[bb2][tt]*vv;
        }
        v += __shfl_down(v,4,8); v += __shfl_down(v,2,8); v += __shfl_down(v,1,8);
        if(part==0) Ds[bb2][512+j] = v*sm[8+bb2];
      }
      __syncthreads();
      {
        int c = cg*256+t, kb = hoff + sub*16;
        const float* wp = p.sao + lE2 + (size_t)kb*EE + c;
        float a0=0,a1=0;
        #pragma unroll
        for(int j2=0;j2<16;j2++){ float w=wp[(size_t)j2*EE]; a0+=Ds[0][512+j2]*w; a1+=Ds[1][512+j2]*w; }
        atomicAdd(&accL[AY+c],a0); atomicAdd(&accL[AY+EE+c],a1);
      }
      if (cg==0 && sub==0){    // write new KV row for head h
        int bb2=t>>7, kv=(t>>6)&1, c2=t&63;
        float val = accL[(kv?AV:AK) + bb2*EE + hoff + c2];
        float* dst = (kv? p.values_out : p.keys_out)
                   + (size_t)l*KVL + (size_t)bb2*KVB + (size_t)tiv*EE + hoff + c2;
        *dst = val;
      }
    } else {
      // 768 idle blocks: prefetch f0 and f1 (this layer) into LLC
      int pb = bkid - 256;
      prefetch4((const float4*)(p.f0 + lEG), (size_t)EE*GG/4, pb, 768);
      prefetch4((const float4*)(p.f1 + lEG), (size_t)EE*GG/4, pb, 768);
    }
    gridbar(bar, g++);

    // ===== stage D: ds2 = dsi + LN(y)*sas+sab ; x2=LN(ds2)+pre_ca_b ; qc = x2@caq (512 blocks)
    if (bkid < 512){
      float mu0,rs0,mu1,rs1;
      ln_stats_g(accL+AY, EE, sm, mu0,rs0,mu1,rs1);
      for(int i=t;i<EE;i+=256){ float sc=p.sas[lE+i], bi=p.sab[lE+i];
        Ds[0][i]=dsi[i]    + (accL[AY+i]-mu0)*rs0*sc + bi;
        Ds[1][i]=dsi[EE+i] + (accL[AY+EE+i]-mu1)*rs1*sc + bi; }
      ln_stats_l(Ds, sm, mu0,rs0,mu1,rs1);
      for(int i=t;i<EE;i+=256){ float bi=p.pre_ca_b[lE+i];
        Xs[0][i]=(Ds[0][i]-mu0)*rs0+bi; Xs[1][i]=(Ds[1][i]-mu1)*rs1+bi; }
      __syncthreads();
      int cg=bkid&3, ks=bkid>>2;               // 4 cg x 128 ks, CH=8
      int c=cg*256+t, k0=ks*8;
      const float* wp = p.caq + lE2 + (size_t)k0*EE + c;
      float a0=0,a1=0;
      #pragma unroll
      for(int k=0;k<8;k++){ float w=*wp; wp+=EE; a0+=Xs[0][k0+k]*w; a1+=Xs[1][k0+k]*w; }
      atomicAdd(&accL[AQC+c],a0); atomicAdd(&accL[AQC+EE+c],a1);
    } else {
      int pb = bkid - 512;                     // 512 idle blocks
      if (l < 11){                             // next layer saq/sak/sav
        prefetch4((const float4*)(p.saq + lE2 + (size_t)EE*EE), (size_t)EE*EE/4, pb, 512);
        prefetch4((const float4*)(p.sak + lE2 + (size_t)EE*EE), (size_t)EE*EE/4, pb, 512);
        prefetch4((const float4*)(p.sav + lE2 + (size_t)EE*EE), (size_t)EE*EE/4, pb, 512);
      } else {
        prefetch4((const float4*)p.lm_w, (size_t)EE*VV/4/3, pb, 512);
      }
    }
    gridbar(bar, g++);

    // ===== stage F: cross-attention (inline) + y2 = attn2 @ cao (256 blocks)
    if (bkid < 256){
      int cg=bkid&3, h=(bkid>>2)&15, sub=(bkid>>6)&3, hoff=h*64;
      const float* ek = p.ws + OFF_EK;
      const float* ev = p.ws + OFF_EV;
      if (t < 128){ int bb2=t>>6, c2=t&63; Ds[bb2][c2] = accL[AQC + bb2*EE + hoff + c2]*0.125f; }
      __syncthreads();
      if (t < 128){
        int bb2=t>>6, tt=t&63;
        const float* kr = ek + ((size_t)l*128 + bb2*64 + tt)*EE + hoff;
        float d=0;
        #pragma unroll
        for(int c2=0;c2<64;c2++) d += Ds[bb2][c2]*kr[c2];
        int mi = bb2*64+tt;
        bool valid = (p.maski[mi]!=0) || (((const unsigned char*)p.maski)[mi]!=0);
        att[bb2][tt] = valid ? d : -3.4e38f;
      }
      __syncthreads();
      int wv=t>>6, l2=t&63;
      if (wv<2){
        float sc = att[wv][l2];
        float m = sc;
        #pragma unroll
        for(int o=32;o;o>>=1) m=fmaxf(m,__shfl_xor(m,o));
        float e = (sc>-1e37f)? __expf(sc-m) : 0.f;
        att[wv][l2]=e; float s=e;
        #pragma unroll
        for(int o=32;o;o>>=1) s+=__shfl_xor(s,o);
        if(l2==0) sm[8+wv]=1.f/s;
      }
      __syncthreads();
      {
        int bb2=t>>7, j=(t>>3)&15, part=t&7, colh=sub*16+j;
        float v=0;
        for(int tt=part; tt<64; tt+=8)
          v += att[bb2][tt]*ev[((size_t)l*128 + bb2*64 + tt)*EE + hoff + colh];
        v += __shfl_down(v,4,8); v += __shfl_down(v,2,8); v += __shfl_down(v,1,8);
        if(part==0) Ds[bb2][512+j] = v*sm[8+bb2];
      }
      __syncthreads();
      {
        int c = cg*256+t, kb = hoff + sub*16;
        const float* wp = p.cao + lE2 + (size_t)kb*EE + c;
        float a0=0,a1=0;
        #pragma unroll
        for(int j2=0;j2<16;j2++){ float w=wp[(size_t)j2*EE]; a0+=Ds[0][512+j2]*w; a1+=Ds[1][512+j2]*w; }
        atomicAdd(&accL[AY2+c],a0); atomicAdd(&accL[AY2+EE+c],a1);
      }
    } else if (bkid < 512){
      // 256 blocks: prefetch f2 (this layer)
      prefetch4((const float4*)(p.f2 + lGE), (size_t)GG*EE/4, bkid-256, 256);
    } else {
      // 512 blocks: prefetch lm_head slice for late layers
      if (l >= 9){
        size_t n4 = (size_t)EE*VV/4, sl = n4/3;
        prefetch4((const float4*)p.lm_w + (size_t)(l-9)*sl, sl, bkid-512, 512);
      }
    }
    gridbar(bar, g++);

    // ===== stage G: ds3 chain ; z=LN(ds3)+g0b ; a=z@f0, b=z@f1 (1012 blocks)
    if (bkid < 1012){
      build_ds3(dsi, accL, p.sas+lE, p.sab+lE, p.cas+lE, p.cab+lE, Ds, sm);
      float mu0,rs0,mu1,rs1;
      ln_stats_l(Ds, sm, mu0,rs0,mu1,rs1);
      for(int i=t;i<EE;i+=256){ float bi=p.g0b[lE+i];
        Xs[0][i]=(Ds[0][i]-mu0)*rs0+bi; Xs[1][i]=(Ds[1][i]-mu1)*rs1+bi; }
      __syncthreads();
      int cg = bkid % 22, ks = bkid / 22;      // 22 cg x 46 ks, CH=23
      int k0 = ks*23;
      if (k0 < EE){
        int k1 = k0+23; if (k1>EE) k1=EE;
        int c = cg*256+t;
        if (c < 5460){
          int sel = (c>=GG), cc = sel? c-GG : c;
          const float* W = (sel? p.f1 : p.f0) + lEG;
          float* O = accL + (sel? AB2 : AA);
          const float* wp = W + (size_t)k0*GG + cc;
          float a0=0,a1=0;
          #pragma unroll 4
          for(int k=k0;k<k1;k++){ float w=*wp; wp+=GG; a0+=Xs[0][k]*w; a1+=Xs[1][k]*w; }
          atomicAdd(&O[cc],a0); atomicAdd(&O[GG+cc],a1);
        }
      }
    }
    gridbar(bar, g++);

    // ===== stage H: t=gelu(a)*b ; z2=LN(t)+g1b ; ds4 = ds3 + z2@f2 (680 blocks)
    if (bkid < 680){
      int cg=bkid&3, ks=bkid>>2;               // 4 cg x 170 ks, CH=17
      if (ks==0) build_ds3(dsi, accL, p.sas+lE, p.sab+lE, p.cas+lE, p.cab+lE, Ds, sm);
      float s0=0,q0=0,s1=0,q1=0;
      for(int i=t;i<GG;i+=256){
        float a0v=accL[AA+i], a1v=accL[AA+GG+i];
        float b0v=accL[AB2+i], b1v=accL[AB2+GG+i];
        float g0v=0.5f*a0v*(1.f+erff(a0v*0.70710678118654752f));
        float g1v=0.5f*a1v*(1.f+erff(a1v*0.70710678118654752f));
        float t0=g0v*b0v, t1=g1v*b1v;
        Xs[0][i]=t0; Xs[1][i]=t1;
        s0+=t0;q0+=t0*t0;s1+=t1;q1+=t1*t1;
      }
      red4(sm,s0,q0,s1,q1);
      float mu0=s0/GG, mu1=s1/GG;
      float rs0=rsqrtf(fmaxf(q0/GG-mu0*mu0,0.f)+EPS), rs1=rsqrtf(fmaxf(q1/GG-mu1*mu1,0.f)+EPS);
      for(int i=t;i<GG;i+=256){ float bi=p.g1b[lG+i];
        Xs[0][i]=(Xs[0][i]-mu0)*rs0+bi; Xs[1][i]=(Xs[1][i]-mu1)*rs1+bi; }
      __syncthreads();
      int k0=ks*17;
      if (k0 < GG){
        int k1=k0+17; if (k1>GG) k1=GG;
        int c=cg*256+t;
        float a0 = (ks==0)? Ds[0][c] : 0.f;
        float a1 = (ks==0)? Ds[1][c] : 0.f;
        const float* wp = p.f2 + lGE + (size_t)k0*EE + c;
        #pragma unroll 4
        for(int k=k0;k<k1;k++){ float w=*wp; wp+=EE; a0+=Xs[0][k]*w; a1+=Xs[1][k]*w; }
        atomicAdd(&ds4[c],a0); atomicAdd(&ds4[EE+c],a1);
      }
    }
    gridbar(bar, g++);
  }

  // ===== final: logits = (LN(ds,final_b)) @ lm_head (975 blocks)
  if (bkid < 975){
    const float* dsf = p.ws + OFF_DS + (size_t)36*2048;
    float mu0,rs0,mu1,rs1;
    ln_stats_g(dsf, EE, sm, mu0,rs0,mu1,rs1);
    for(int i=t;i<EE;i+=256){ float bi=p.final_b[i];
      Xs[0][i]=(dsf[i]-mu0)*rs0+bi; Xs[1][i]=(dsf[EE+i]-mu1)*rs1+bi; }
    __syncthreads();
    int cg=bkid%65, ks=bkid/65;                // 65 cg x 15 ks, CH=69
    int k0=ks*69, k1=k0+69; if (k1>EE) k1=EE;
    int c=cg*256+t;
    if (c < VV && k0 < EE){
      const float* wp = p.lm_w + (size_t)k0*VV + c;
      float a0=0,a1=0;
      #pragma unroll 4
      for(int k=k0;k<k1;k++){ float w=*wp; wp+=VV; a0+=Xs[0][k]*w; a1+=Xs[1][k]*w; }
      atomicAdd(&p.logits[c],a0); atomicAdd(&p.logits[VV+c],a1);
    }
  }
}

extern "C" void kernel_launch(void* const* d_in, const int* in_sizes, int n_in,
                              void* d_out, int out_size, void* d_ws, size_t ws_size,
                              hipStream_t stream){
  (void)in_sizes; (void)n_in; (void)out_size; (void)ws_size;
  float* out = (float*)d_out;
  float* ws = (float*)d_ws;

  MegaP P;
  P.enc        = (const float*)d_in[0];
  P.keys_in    = (const float*)d_in[1];
  P.values_in  = (const float*)d_in[2];
  P.maski      = (const int*)d_in[3];
  P.pt         = (const int*)d_in[4];
  P.ti         = (const int*)d_in[5];
  P.tok        = (const float*)d_in[6];
  P.pos        = (const float*)d_in[7];
  P.ln_s       = (const float*)d_in[8];
  P.ln_b       = (const float*)d_in[9];
  P.final_b    = (const float*)d_in[10];
  P.lm_w       = (const float*)d_in[11];
  P.pre_sa_b   = (const float*)d_in[12];
  P.saq        = (const float*)d_in[13];
  P.sak        = (const float*)d_in[14];
  P.sav        = (const float*)d_in[15];
  P.sao        = (const float*)d_in[16];
  P.sas        = (const float*)d_in[17];
  P.sab        = (const float*)d_in[18];
  P.pre_ca_b   = (const float*)d_in[19];
  P.caq        = (const float*)d_in[20];
  const float* cak = (const float*)d_in[21];
  const float* cav = (const float*)d_in[22];
  P.cao        = (const float*)d_in[23];
  P.cas        = (const float*)d_in[24];
  P.cab        = (const float*)d_in[25];
  P.g0b        = (const float*)d_in[26];
  P.f0         = (const float*)d_in[27];
  P.f1         = (const float*)d_in[28];
  P.g1b        = (const float*)d_in[29];
  P.f2         = (const float*)d_in[30];
  P.logits     = out;
  P.keys_out   = out + (size_t)2*VV;
  P.values_out = P.keys_out + (size_t)LAYERS*KVL;
  P.ws         = ws;

  hipMemsetAsync(ws + OFF_DS, 0, (size_t)ZERO_FLOATS*sizeof(float), stream);
  hipMemsetAsync(P.logits, 0, (size_t)2*VV*sizeof(float), stream);

  k_ekev<<<dim3(32,24),256,0,stream>>>(P.enc, cak, cav, ws);
  k_mega<<<NBLK,256,0,stream>>>(P);
}

// Round 5
// 1739.938 us; speedup vs baseline: 15.9995x; 15.9995x over previous
//
#include <hip/hip_runtime.h>
#include <math.h>

#define LAYERS 12
#define EE 1024
#define GG 2730
#define VV 16416
#define EPS 1e-6f

// ---- workspace layout (float offsets) ----
#define OFF_EK 0
#define OFF_EV 1572864
#define OFF_DS 3145728
#define NSLOT 37
#define OFF_ACC (OFF_DS + NSLOT*2048)
#define ACC_STRIDE 28672
#define AQ 0
#define AK 2048
#define AV 4096
#define AY 6144
#define AQC 8192
#define AY2 10240
#define AA 12288
#define AB2 17748
#define ACC_TOTAL (LAYERS*ACC_STRIDE)
#define ZERO_FLOATS (NSLOT*2048 + ACC_TOTAL)

#define KVL 524288   // floats per layer per cache (2 batches x 256 x 1024)
#define KVB 262144   // floats per batch

struct MegaP {
  const float* enc; const float* keys_in; const float* values_in;
  const int* maski; const int* pt; const int* ti;
  const float* tok; const float* pos; const float* ln_s; const float* ln_b;
  const float* final_b; const float* lm_w;
  const float* pre_sa_b; const float* saq; const float* sak; const float* sav;
  const float* sao; const float* sas; const float* sab;
  const float* pre_ca_b; const float* caq; const float* ckw; const float* cvw;
  const float* cao; const float* cas; const float* cab;
  const float* g0b; const float* f0; const float* f1; const float* g1b; const float* f2;
  float* logits; float* keys_out; float* values_out; float* ws;
};

__device__ __forceinline__ void red4(float* sm, float& a, float& b, float& c, float& d){
  #pragma unroll
  for(int o=32;o;o>>=1){ a+=__shfl_down(a,o); b+=__shfl_down(b,o); c+=__shfl_down(c,o); d+=__shfl_down(d,o); }
  int w=threadIdx.x>>6, l=threadIdx.x&63;
  __syncthreads();
  if(l==0){ sm[w]=a; sm[4+w]=b; sm[8+w]=c; sm[12+w]=d; }
  __syncthreads();
  a=sm[0]+sm[1]+sm[2]+sm[3]; b=sm[4]+sm[5]+sm[6]+sm[7];
  c=sm[8]+sm[9]+sm[10]+sm[11]; d=sm[12]+sm[13]+sm[14]+sm[15];
}

__device__ __forceinline__ void ln_stats_g(const float* v, int K, float* sm,
    float& mu0, float& rs0, float& mu1, float& rs1){
  float s0=0,q0=0,s1=0,q1=0;
  for(int i=threadIdx.x;i<K;i+=256){ float a=v[i], b=v[K+i]; s0+=a;q0+=a*a;s1+=b;q1+=b*b; }
  red4(sm,s0,q0,s1,q1);
  mu0=s0/K; mu1=s1/K;
  rs0=rsqrtf(fmaxf(q0/K-mu0*mu0,0.f)+EPS);
  rs1=rsqrtf(fmaxf(q1/K-mu1*mu1,0.f)+EPS);
}

__device__ __forceinline__ void ln_stats_l(float (*Ds)[1024], float* sm,
    float& mu0, float& rs0, float& mu1, float& rs1){
  float s0=0,q0=0,s1=0,q1=0;
  for(int i=threadIdx.x;i<EE;i+=256){ float a=Ds[0][i], b=Ds[1][i]; s0+=a;q0+=a*a;s1+=b;q1+=b*b; }
  red4(sm,s0,q0,s1,q1);
  mu0=s0/EE; mu1=s1/EE;
  rs0=rsqrtf(fmaxf(q0/EE-mu0*mu0,0.f)+EPS);
  rs1=rsqrtf(fmaxf(q1/EE-mu1*mu1,0.f)+EPS);
}

// ds3 = dsi + LN(AY)*sas+sab + LN(AY2)*cas+cab  -> Ds
__device__ __forceinline__ void build_ds3(const float* dsi, const float* accL,
    const float* sasl, const float* sabl, const float* casl, const float* cabl,
    float (*Ds)[1024], float* sm){
  float mu0,rs0,mu1,rs1;
  ln_stats_g(accL+AY, EE, sm, mu0,rs0,mu1,rs1);
  for(int i=threadIdx.x;i<EE;i+=256){ float sc=sasl[i], bi=sabl[i];
    Ds[0][i]=dsi[i]    + (accL[AY+i]-mu0)*rs0*sc + bi;
    Ds[1][i]=dsi[EE+i] + (accL[AY+EE+i]-mu1)*rs1*sc + bi; }
  ln_stats_g(accL+AY2, EE, sm, mu0,rs0,mu1,rs1);
  for(int i=threadIdx.x;i<EE;i+=256){ float sc=casl[i], bi=cabl[i];
    Ds[0][i] += (accL[AY2+i]-mu0)*rs0*sc + bi;
    Ds[1][i] += (accL[AY2+EE+i]-mu1)*rs1*sc + bi; }
}

// ===== k_init: 768 ek/ev GEMM tiles + 256 KV-copy blocks + 1 prelude block
__global__ __launch_bounds__(256)
void k_init(MegaP p){
  __shared__ float As[128][33];
  __shared__ float Bs[32][33];
  const int t=threadIdx.x, bid=blockIdx.x;
  const int tiv=p.ti[0];
  if (bid < 768){
    int lp = bid>>5, cx = bid&31;
    int l = lp>>1, proj = lp&1;
    const float* Wt = (proj? p.cvw : p.ckw) + (size_t)l*EE*EE;
    float* out = p.ws + (proj? OFF_EV : OFF_EK) + (size_t)l*128*EE;
    int c0 = cx*32;
    int tx=t&7, ty=t>>3;
    float acc[4][4];
    #pragma unroll
    for(int i=0;i<4;i++){ acc[i][0]=0;acc[i][1]=0;acc[i][2]=0;acc[i][3]=0; }
    for (int k0=0;k0<EE;k0+=32){
      for (int i=t;i<128*32;i+=256){ int r=i>>5, k=i&31; As[r][k] = p.enc[(size_t)r*EE + k0+k]; }
      for (int i=t;i<32*32;i+=256){ int k=i>>5, c=i&31; Bs[k][c] = Wt[(size_t)(k0+k)*EE + c0+c]; }
      __syncthreads();
      #pragma unroll 8
      for (int k=0;k<32;k++){
        float b0=Bs[k][tx*4+0], b1=Bs[k][tx*4+1], b2=Bs[k][tx*4+2], b3=Bs[k][tx*4+3];
        #pragma unroll
        for (int rr=0;rr<4;rr++){
          float av = As[ty+32*rr][k];
          acc[rr][0]+=av*b0; acc[rr][1]+=av*b1; acc[rr][2]+=av*b2; acc[rr][3]+=av*b3;
        }
      }
      __syncthreads();
    }
    #pragma unroll
    for (int rr=0;rr<4;rr++)
      #pragma unroll
      for (int j=0;j<4;j++)
        out[(size_t)(ty+32*rr)*EE + c0 + tx*4+j] = acc[rr][j];
  } else if (bid < 1024){
    // KV cache copy: 3145728 float4 total across both caches, skip row tiv
    int gid = (bid-768)*256 + t;
    #pragma unroll 4
    for (int it=0; it<48; it++){
      int idx4 = gid + it*65536;
      int kv = idx4 >= 1572864;
      int r  = idx4 - (kv? 1572864 : 0);
      int ll = r>>17, r2 = r&131071, bb = r2>>16, r3 = r2&65535, tt = r3>>8, e4 = r3&255;
      if (tt == tiv) continue;
      size_t off = (size_t)ll*KVL + (size_t)bb*KVB + (size_t)tt*EE + (size_t)e4*4;
      float4 v = *(const float4*)((kv? p.values_in : p.keys_in) + off);
      *(float4*)((kv? p.values_out : p.keys_out) + off) = v;
    }
  } else {
    // prelude: ds0 = LN(tok[pt]+pos[ti], ln_s, ln_b), both batch rows
    float* ev = &As[0][0];
    float* smv = &Bs[0][0];
    int ptv = p.pt[0];
    float s0=0,q0=0,d1=0,d2=0;
    for(int i=t;i<EE;i+=256){ float v=p.tok[(size_t)ptv*EE+i]+p.pos[(size_t)tiv*EE+i]; ev[i]=v; s0+=v; q0+=v*v; }
    red4(smv,s0,q0,d1,d2);
    float mu=s0/EE, rs=rsqrtf(fmaxf(q0/EE-mu*mu,0.f)+EPS);
    float* ds0 = p.ws + OFF_DS;
    __syncthreads();
    for(int i=t;i<EE;i+=256){ float y=(ev[i]-mu)*rs*p.ln_s[i]+p.ln_b[i]; ds0[i]=y; ds0[EE+i]=y; }
  }
}

// ===== stage A: x=LN(dsi)+pre_sa_b ; q,k,v = x@{saq,sak,sav}. grid (3,86)
__global__ __launch_bounds__(256)
void k_qkv(MegaP p, int l){
  __shared__ float Xs[2][1024];
  __shared__ float sm[16];
  const int t=threadIdx.x;
  const float* dsi = p.ws + OFF_DS + (size_t)(3*l)*2048;
  float* accL = p.ws + OFF_ACC + (size_t)l*ACC_STRIDE;
  const size_t lE2=(size_t)l*EE*EE, lE=(size_t)l*EE;
  float mu0,rs0,mu1,rs1;
  ln_stats_g(dsi, EE, sm, mu0,rs0,mu1,rs1);
  for(int i=t;i<EE;i+=256){ float bi=p.pre_sa_b[lE+i];
    Xs[0][i]=(dsi[i]-mu0)*rs0+bi; Xs[1][i]=(dsi[EE+i]-mu1)*rs1+bi; }
  __syncthreads();
  int c4 = blockIdx.x*256 + t;           // [0,768)
  int col = c4*4, sel = col>>10, cc = col&1023;
  const float* W = (sel==0? p.saq : sel==1? p.sak : p.sav) + lE2;
  float* O = accL + (sel==0? AQ : sel==1? AK : AV);
  int k0 = blockIdx.y*12, k1 = k0+12; if (k1>EE) k1=EE;
  const float4* wp = (const float4*)(W + (size_t)k0*EE + cc);
  float a0=0,a1=0,a2=0,a3=0,b0=0,b1=0,b2=0,b3=0;
  for(int k=k0;k<k1;k++){
    float4 w=*wp; wp+=256;
    float x0=Xs[0][k], x1=Xs[1][k];
    a0+=x0*w.x; a1+=x0*w.y; a2+=x0*w.z; a3+=x0*w.w;
    b0+=x1*w.x; b1+=x1*w.y; b2+=x1*w.z; b3+=x1*w.w;
  }
  atomicAdd(&O[cc+0],a0); atomicAdd(&O[cc+1],a1); atomicAdd(&O[cc+2],a2); atomicAdd(&O[cc+3],a3);
  atomicAdd(&O[EE+cc+0],b0); atomicAdd(&O[EE+cc+1],b1); atomicAdd(&O[EE+cc+2],b2); atomicAdd(&O[EE+cc+3],b3);
}

// ===== stage C: fused self-attention + y = attn @ sao. grid 256. Writes new KV row.
__global__ __launch_bounds__(256)
void k_selfo(MegaP p, int l){
  __shared__ float Ds[2][1024];
  __shared__ float att[2][256];
  __shared__ float sm[16];
  const int t=threadIdx.x, bkid=blockIdx.x, tiv=p.ti[0];
  float* accL = p.ws + OFF_ACC + (size_t)l*ACC_STRIDE;
  const size_t lE2=(size_t)l*EE*EE;
  int cg=bkid&3, h=(bkid>>2)&15, sub=(bkid>>6)&3, hoff=h*64;
  if (t < 128){ int bb2=t>>6, c2=t&63; Ds[bb2][c2] = accL[AQ + bb2*EE + hoff + c2]*0.125f; }
  __syncthreads();
  for(int bb2=0;bb2<2;bb2++)
    for(int tt=t; tt<=tiv; tt+=256){
      const float* kr = (tt<tiv) ? (p.keys_in + (size_t)l*KVL + (size_t)bb2*KVB + (size_t)tt*EE + hoff)
                                 : (accL + AK + bb2*EE + hoff);
      float d=0;
      #pragma unroll
      for(int c2=0;c2<64;c2++) d += Ds[bb2][c2]*kr[c2];
      att[bb2][tt] = d;
    }
  __syncthreads();
  int wv=t>>6, l2=t&63;
  if (wv<2){
    float m=-3.4e38f;
    for(int tt=l2; tt<=tiv; tt+=64) m=fmaxf(m, att[wv][tt]);
    #pragma unroll
    for(int o=32;o;o>>=1) m=fmaxf(m,__shfl_xor(m,o));
    float s=0;
    for(int tt=l2; tt<=tiv; tt+=64){ float e=__expf(att[wv][tt]-m); att[wv][tt]=e; s+=e; }
    #pragma unroll
    for(int o=32;o;o>>=1) s+=__shfl_xor(s,o);
    if(l2==0) sm[8+wv]=1.f/s;
  }
  __syncthreads();
  {
    int bb2=t>>7, j=(t>>3)&15, part=t&7, colh=sub*16+j;
    float v=0;
    for(int tt=part; tt<=tiv; tt+=8){
      float vv = (tt<tiv)? p.values_in[(size_t)l*KVL + (size_t)bb2*KVB + (size_t)tt*EE + hoff + colh]
                         : accL[AV + bb2*EE + hoff + colh];
      v += att[bb2][tt]*vv;
    }
    v += __shfl_down(v,4,8); v += __shfl_down(v,2,8); v += __shfl_down(v,1,8);
    if(part==0) Ds[bb2][512+j] = v*sm[8+bb2];
  }
  __syncthreads();
  {
    int c = cg*256+t, kb = hoff + sub*16;
    const float* wp = p.sao + lE2 + (size_t)kb*EE + c;
    float a0=0,a1=0;
    #pragma unroll
    for(int j2=0;j2<16;j2++){ float w=wp[(size_t)j2*EE]; a0+=Ds[0][512+j2]*w; a1+=Ds[1][512+j2]*w; }
    atomicAdd(&accL[AY+c],a0); atomicAdd(&accL[AY+EE+c],a1);
  }
  if (cg==0 && sub==0){
    int bb2=t>>7, kv=(t>>6)&1, c2=t&63;
    float val = accL[(kv?AV:AK) + bb2*EE + hoff + c2];
    float* dst = (kv? p.values_out : p.keys_out)
               + (size_t)l*KVL + (size_t)bb2*KVB + (size_t)tiv*EE + hoff + c2;
    *dst = val;
  }
}

// ===== stage D: ds2 = dsi + LN(y)*sas+sab ; x2=LN(ds2)+pre_ca_b ; qc = x2@caq. grid 128
__global__ __launch_bounds__(256)
void k_ds2caq(MegaP p, int l){
  __shared__ float Xs[2][1024];
  __shared__ float Ds[2][1024];
  __shared__ float sm[16];
  const int t=threadIdx.x;
  const float* dsi = p.ws + OFF_DS + (size_t)(3*l)*2048;
  float* accL = p.ws + OFF_ACC + (size_t)l*ACC_STRIDE;
  const size_t lE2=(size_t)l*EE*EE, lE=(size_t)l*EE;
  float mu0,rs0,mu1,rs1;
  ln_stats_g(accL+AY, EE, sm, mu0,rs0,mu1,rs1);
  for(int i=t;i<EE;i+=256){ float sc=p.sas[lE+i], bi=p.sab[lE+i];
    Ds[0][i]=dsi[i]    + (accL[AY+i]-mu0)*rs0*sc + bi;
    Ds[1][i]=dsi[EE+i] + (accL[AY+EE+i]-mu1)*rs1*sc + bi; }
  ln_stats_l(Ds, sm, mu0,rs0,mu1,rs1);
  for(int i=t;i<EE;i+=256){ float bi=p.pre_ca_b[lE+i];
    Xs[0][i]=(Ds[0][i]-mu0)*rs0+bi; Xs[1][i]=(Ds[1][i]-mu1)*rs1+bi; }
  __syncthreads();
  int col = t*4;
  int k0 = blockIdx.x*8, k1 = k0+8;
  const float4* wp = (const float4*)(p.caq + lE2 + (size_t)k0*EE + col);
  float a0=0,a1=0,a2=0,a3=0,b0=0,b1=0,b2=0,b3=0;
  for(int k=k0;k<k1;k++){
    float4 w=*wp; wp+=256;
    float x0=Xs[0][k], x1=Xs[1][k];
    a0+=x0*w.x; a1+=x0*w.y; a2+=x0*w.z; a3+=x0*w.w;
    b0+=x1*w.x; b1+=x1*w.y; b2+=x1*w.z; b3+=x1*w.w;
  }
  float* O = accL + AQC;
  atomicAdd(&O[col+0],a0); atomicAdd(&O[col+1],a1); atomicAdd(&O[col+2],a2); atomicAdd(&O[col+3],a3);
  atomicAdd(&O[EE+col+0],b0); atomicAdd(&O[EE+col+1],b1); atomicAdd(&O[EE+col+2],b2); atomicAdd(&O[EE+col+3],b3);
}

// ===== stage F: fused cross-attention + y2 = attn2 @ cao. grid 256
__global__ __launch_bounds__(256)
void k_crosso(MegaP p, int l){
  __shared__ float Ds[2][1024];
  __shared__ float att[2][256];
  __shared__ float sm[16];
  const int t=threadIdx.x, bkid=blockIdx.x;
  float* accL = p.ws + OFF_ACC + (size_t)l*ACC_STRIDE;
  const size_t lE2=(size_t)l*EE*EE;
  int cg=bkid&3, h=(bkid>>2)&15, sub=(bkid>>6)&3, hoff=h*64;
  const float* ek = p.ws + OFF_EK;
  const float* ev = p.ws + OFF_EV;
  if (t < 128){ int bb2=t>>6, c2=t&63; Ds[bb2][c2] = accL[AQC + bb2*EE + hoff + c2]*0.125f; }
  __syncthreads();
  if (t < 128){
    int bb2=t>>6, tt=t&63;
    const float* kr = ek + ((size_t)l*128 + bb2*64 + tt)*EE + hoff;
    float d=0;
    #pragma unroll
    for(int c2=0;c2<64;c2++) d += Ds[bb2][c2]*kr[c2];
    int mi = bb2*64+tt;
    bool valid = (p.maski[mi]!=0) || (((const unsigned char*)p.maski)[mi]!=0);
    att[bb2][tt] = valid ? d : -3.4e38f;
  }
  __syncthreads();
  int wv=t>>6, l2=t&63;
  if (wv<2){
    float sc = att[wv][l2];
    float m = sc;
    #pragma unroll
    for(int o=32;o;o>>=1) m=fmaxf(m,__shfl_xor(m,o));
    float e = (sc>-1e37f)? __expf(sc-m) : 0.f;
    att[wv][l2]=e; float s=e;
    #pragma unroll
    for(int o=32;o;o>>=1) s+=__shfl_xor(s,o);
    if(l2==0) sm[8+wv]=1.f/s;
  }
  __syncthreads();
  {
    int bb2=t>>7, j=(t>>3)&15, part=t&7, colh=sub*16+j;
    float v=0;
    for(int tt=part; tt<64; tt+=8)
      v += att[bb2][tt]*ev[((size_t)l*128 + bb2*64 + tt)*EE + hoff + colh];
    v += __shfl_down(v,4,8); v += __shfl_down(v,2,8); v += __shfl_down(v,1,8);
    if(part==0) Ds[bb2][512+j] = v*sm[8+bb2];
  }
  __syncthreads();
  {
    int c = cg*256+t, kb = hoff + sub*16;
    const float* wp = p.cao + lE2 + (size_t)kb*EE + c;
    float a0=0,a1=0;
    #pragma unroll
    for(int j2=0;j2<16;j2++){ float w=wp[(size_t)j2*EE]; a0+=Ds[0][512+j2]*w; a1+=Ds[1][512+j2]*w; }
    atomicAdd(&accL[AY2+c],a0); atomicAdd(&accL[AY2+EE+c],a1);
  }
}

// ===== stage G: ds3 ; z=LN(ds3)+g0b ; a=z@f0, b=z@f1. grid (11,24), float2 loads
__global__ __launch_bounds__(256)
void k_glu01(MegaP p, int l){
  __shared__ float Xs[2][1024];
  __shared__ float Ds[2][1024];
  __shared__ float sm[16];
  const int t=threadIdx.x;
  const float* dsi = p.ws + OFF_DS + (size_t)(3*l)*2048;
  float* accL = p.ws + OFF_ACC + (size_t)l*ACC_STRIDE;
  const size_t lEG=(size_t)l*EE*GG, lE=(size_t)l*EE;
  build_ds3(dsi, accL, p.sas+lE, p.sab+lE, p.cas+lE, p.cab+lE, Ds, sm);
  float mu0,rs0,mu1,rs1;
  ln_stats_l(Ds, sm, mu0,rs0,mu1,rs1);
  for(int i=t;i<EE;i+=256){ float bi=p.g0b[lE+i];
    Xs[0][i]=(Ds[0][i]-mu0)*rs0+bi; Xs[1][i]=(Ds[1][i]-mu1)*rs1+bi; }
  __syncthreads();
  int c2 = blockIdx.x*256 + t;
  if (c2 < 2730){
    int sel = (c2>=1365), cc2 = sel? c2-1365 : c2, col = cc2*2;
    const float* W = (sel? p.f1 : p.f0) + lEG;
    float* O = accL + (sel? AB2 : AA);
    int k0 = blockIdx.y*43, k1 = k0+43; if (k1>EE) k1=EE;
    const float2* wp = (const float2*)(W + (size_t)k0*GG + col);
    float a0=0,a1=0,b0=0,b1=0;
    for(int k=k0;k<k1;k++){
      float2 w=*wp; wp+=1365;
      float x0=Xs[0][k], x1=Xs[1][k];
      a0+=x0*w.x; a1+=x0*w.y; b0+=x1*w.x; b1+=x1*w.y;
    }
    atomicAdd(&O[col+0],a0); atomicAdd(&O[col+1],a1);
    atomicAdd(&O[GG+col+0],b0); atomicAdd(&O[GG+col+1],b1);
  }
}

// ===== stage H: t=gelu(a)*b ; z2=LN(t)+g1b ; ds4 = ds3 + z2@f2. grid 128
__global__ __launch_bounds__(256)
void k_glu2(MegaP p, int l){
  __shared__ float Xs[2][2736];
  __shared__ float Ds[2][1024];
  __shared__ float sm[16];
  const int t=threadIdx.x, ks=blockIdx.x;
  const float* dsi = p.ws + OFF_DS + (size_t)(3*l)*2048;
  float* ds4 = p.ws + OFF_DS + (size_t)(3*l+3)*2048;
  float* accL = p.ws + OFF_ACC + (size_t)l*ACC_STRIDE;
  const size_t lGE=(size_t)l*GG*EE, lE=(size_t)l*EE, lG=(size_t)l*GG;
  if (ks==0) build_ds3(dsi, accL, p.sas+lE, p.sab+lE, p.cas+lE, p.cab+lE, Ds, sm);
  float s0=0,q0=0,s1=0,q1=0;
  for(int i=t;i<GG;i+=256){
    float a0v=accL[AA+i], a1v=accL[AA+GG+i];
    float b0v=accL[AB2+i], b1v=accL[AB2+GG+i];
    float g0v=0.5f*a0v*(1.f+erff(a0v*0.70710678118654752f));
    float g1v=0.5f*a1v*(1.f+erff(a1v*0.70710678118654752f));
    float t0=g0v*b0v, t1=g1v*b1v;
    Xs[0][i]=t0; Xs[1][i]=t1;
    s0+=t0;q0+=t0*t0;s1+=t1;q1+=t1*t1;
  }
  red4(sm,s0,q0,s1,q1);
  float mu0=s0/GG, mu1=s1/GG;
  float rs0=rsqrtf(fmaxf(q0/GG-mu0*mu0,0.f)+EPS), rs1=rsqrtf(fmaxf(q1/GG-mu1*mu1,0.f)+EPS);
  for(int i=t;i<GG;i+=256){ float bi=p.g1b[lG+i];
    Xs[0][i]=(Xs[0][i]-mu0)*rs0+bi; Xs[1][i]=(Xs[1][i]-mu1)*rs1+bi; }
  __syncthreads();
  int col = t*4;
  int k0 = ks*22, k1 = k0+22; if (k1>GG) k1=GG;
  float a0=0,a1=0,a2=0,a3=0,b0=0,b1=0,b2=0,b3=0;
  if (ks==0){
    a0=Ds[0][col]; a1=Ds[0][col+1]; a2=Ds[0][col+2]; a3=Ds[0][col+3];
    b0=Ds[1][col]; b1=Ds[1][col+1]; b2=Ds[1][col+2]; b3=Ds[1][col+3];
  }
  const float4* wp = (const float4*)(p.f2 + lGE + (size_t)k0*EE + col);
  for(int k=k0;k<k1;k++){
    float4 w=*wp; wp+=256;
    float x0=Xs[0][k], x1=Xs[1][k];
    a0+=x0*w.x; a1+=x0*w.y; a2+=x0*w.z; a3+=x0*w.w;
    b0+=x1*w.x; b1+=x1*w.y; b2+=x1*w.z; b3+=x1*w.w;
  }
  atomicAdd(&ds4[col+0],a0); atomicAdd(&ds4[col+1],a1); atomicAdd(&ds4[col+2],a2); atomicAdd(&ds4[col+3],a3);
  atomicAdd(&ds4[EE+col+0],b0); atomicAdd(&ds4[EE+col+1],b1); atomicAdd(&ds4[EE+col+2],b2); atomicAdd(&ds4[EE+col+3],b3);
}

// ===== final: logits = LN(ds,final_b) @ lm_head. grid (17,16)
__global__ __launch_bounds__(256)
void k_lm(MegaP p){
  __shared__ float Xs[2][1024];
  __shared__ float sm[16];
  const int t=threadIdx.x;
  const float* dsf = p.ws + OFF_DS + (size_t)36*2048;
  float mu0,rs0,mu1,rs1;
  ln_stats_g(dsf, EE, sm, mu0,rs0,mu1,rs1);
  for(int i=t;i<EE;i+=256){ float bi=p.final_b[i];
    Xs[0][i]=(dsf[i]-mu0)*rs0+bi; Xs[1][i]=(dsf[EE+i]-mu1)*rs1+bi; }
  __syncthreads();
  int c4 = blockIdx.x*256 + t;
  int col = c4*4;
  if (col < VV){
    int k0 = blockIdx.y*64, k1 = k0+64;
    const float4* wp = (const float4*)(p.lm_w + (size_t)k0*VV + col);
    float a0=0,a1=0,a2=0,a3=0,b0=0,b1=0,b2=0,b3=0;
    for(int k=k0;k<k1;k++){
      float4 w=*wp; wp+=4104;
      float x0=Xs[0][k], x1=Xs[1][k];
      a0+=x0*w.x; a1+=x0*w.y; a2+=x0*w.z; a3+=x0*w.w;
      b0+=x1*w.x; b1+=x1*w.y; b2+=x1*w.z; b3+=x1*w.w;
    }
    atomicAdd(&p.logits[col+0],a0); atomicAdd(&p.logits[col+1],a1);
    atomicAdd(&p.logits[col+2],a2); atomicAdd(&p.logits[col+3],a3);
    atomicAdd(&p.logits[VV+col+0],b0); atomicAdd(&p.logits[VV+col+1],b1);
    atomicAdd(&p.logits[VV+col+2],b2); atomicAdd(&p.logits[VV+col+3],b3);
  }
}

extern "C" void kernel_launch(void* const* d_in, const int* in_sizes, int n_in,
                              void* d_out, int out_size, void* d_ws, size_t ws_size,
                              hipStream_t stream){
  (void)in_sizes; (void)n_in; (void)out_size; (void)ws_size;
  float* out = (float*)d_out;
  float* ws = (float*)d_ws;

  MegaP P;
  P.enc        = (const float*)d_in[0];
  P.keys_in    = (const float*)d_in[1];
  P.values_in  = (const float*)d_in[2];
  P.maski      = (const int*)d_in[3];
  P.pt         = (const int*)d_in[4];
  P.ti         = (const int*)d_in[5];
  P.tok        = (const float*)d_in[6];
  P.pos        = (const float*)d_in[7];
  P.ln_s       = (const float*)d_in[8];
  P.ln_b       = (const float*)d_in[9];
  P.final_b    = (const float*)d_in[10];
  P.lm_w       = (const float*)d_in[11];
  P.pre_sa_b   = (const float*)d_in[12];
  P.saq        = (const float*)d_in[13];
  P.sak        = (const float*)d_in[14];
  P.sav        = (const float*)d_in[15];
  P.sao        = (const float*)d_in[16];
  P.sas        = (const float*)d_in[17];
  P.sab        = (const float*)d_in[18];
  P.pre_ca_b   = (const float*)d_in[19];
  P.caq        = (const float*)d_in[20];
  P.ckw        = (const float*)d_in[21];
  P.cvw        = (const float*)d_in[22];
  P.cao        = (const float*)d_in[23];
  P.cas        = (const float*)d_in[24];
  P.cab        = (const float*)d_in[25];
  P.g0b        = (const float*)d_in[26];
  P.f0         = (const float*)d_in[27];
  P.f1         = (const float*)d_in[28];
  P.g1b        = (const float*)d_in[29];
  P.f2         = (const float*)d_in[30];
  P.logits     = out;
  P.keys_out   = out + (size_t)2*VV;
  P.values_out = P.keys_out + (size_t)LAYERS*KVL;
  P.ws         = ws;

  hipMemsetAsync(ws + OFF_DS, 0, (size_t)ZERO_FLOATS*sizeof(float), stream);
  hipMemsetAsync(P.logits, 0, (size_t)2*VV*sizeof(float), stream);

  k_init<<<1025,256,0,stream>>>(P);
  for (int l=0;l<LAYERS;l++){
    k_qkv   <<<dim3(3,86), 256,0,stream>>>(P,l);
    k_selfo <<<256,        256,0,stream>>>(P,l);
    k_ds2caq<<<128,        256,0,stream>>>(P,l);
    k_crosso<<<256,        256,0,stream>>>(P,l);
    k_glu01 <<<dim3(11,24),256,0,stream>>>(P,l);
    k_glu2  <<<128,        256,0,stream>>>(P,l);
  }
  k_lm<<<dim3(17,16),256,0,stream>>>(P);
}

// Round 6
// 1160.453 us; speedup vs baseline: 23.9891x; 1.4994x over previous
//
#include <hip/hip_runtime.h>
#include <math.h>

#define LAYERS 12
#define EE 1024
#define GG 2730
#define VV 16416
#define EPS 1e-6f

// ---- workspace layout (float offsets) ----
#define OFF_EK 0
#define OFF_EV 1572864
#define OFF_DS 3145728
#define NSLOT 37
#define OFF_ACC (OFF_DS + NSLOT*2048)
#define ACC_STRIDE 28672
#define AQ 0
#define AK 2048
#define AV 4096
#define AY 6144
#define AQC 8192
#define AY2 10240
#define AA 12288
#define AB2 17748
#define ACC_TOTAL (LAYERS*ACC_STRIDE)
#define ZERO_FLOATS (NSLOT*2048 + ACC_TOTAL)

#define KVL 524288   // floats per layer per cache (2 batches x 256 x 1024)
#define KVB 262144   // floats per batch

struct MegaP {
  const float* enc; const float* keys_in; const float* values_in;
  const int* maski; const int* pt; const int* ti;
  const float* tok; const float* pos; const float* ln_s; const float* ln_b;
  const float* final_b; const float* lm_w;
  const float* pre_sa_b; const float* saq; const float* sak; const float* sav;
  const float* sao; const float* sas; const float* sab;
  const float* pre_ca_b; const float* caq; const float* ckw; const float* cvw;
  const float* cao; const float* cas; const float* cab;
  const float* g0b; const float* f0; const float* f1; const float* g1b; const float* f2;
  float* logits; float* keys_out; float* values_out; float* ws;
};

__device__ __forceinline__ void red4(float* sm, float& a, float& b, float& c, float& d){
  #pragma unroll
  for(int o=32;o;o>>=1){ a+=__shfl_down(a,o); b+=__shfl_down(b,o); c+=__shfl_down(c,o); d+=__shfl_down(d,o); }
  int w=threadIdx.x>>6, l=threadIdx.x&63;
  __syncthreads();
  if(l==0){ sm[w]=a; sm[4+w]=b; sm[8+w]=c; sm[12+w]=d; }
  __syncthreads();
  a=sm[0]+sm[1]+sm[2]+sm[3]; b=sm[4]+sm[5]+sm[6]+sm[7];
  c=sm[8]+sm[9]+sm[10]+sm[11]; d=sm[12]+sm[13]+sm[14]+sm[15];
}

__device__ __forceinline__ void ln_stats_g(const float* v, int K, float* sm,
    float& mu0, float& rs0, float& mu1, float& rs1){
  float s0=0,q0=0,s1=0,q1=0;
  for(int i=threadIdx.x;i<K;i+=256){ float a=v[i], b=v[K+i]; s0+=a;q0+=a*a;s1+=b;q1+=b*b; }
  red4(sm,s0,q0,s1,q1);
  mu0=s0/K; mu1=s1/K;
  rs0=rsqrtf(fmaxf(q0/K-mu0*mu0,0.f)+EPS);
  rs1=rsqrtf(fmaxf(q1/K-mu1*mu1,0.f)+EPS);
}

__device__ __forceinline__ void ln_stats_l(float (*Ds)[1024], float* sm,
    float& mu0, float& rs0, float& mu1, float& rs1){
  float s0=0,q0=0,s1=0,q1=0;
  for(int i=threadIdx.x;i<EE;i+=256){ float a=Ds[0][i], b=Ds[1][i]; s0+=a;q0+=a*a;s1+=b;q1+=b*b; }
  red4(sm,s0,q0,s1,q1);
  mu0=s0/EE; mu1=s1/EE;
  rs0=rsqrtf(fmaxf(q0/EE-mu0*mu0,0.f)+EPS);
  rs1=rsqrtf(fmaxf(q1/EE-mu1*mu1,0.f)+EPS);
}

// ds3 = dsi + LN(AY)*sas+sab + LN(AY2)*cas+cab  -> Ds
__device__ __forceinline__ void build_ds3(const float* dsi, const float* accL,
    const float* sasl, const float* sabl, const float* casl, const float* cabl,
    float (*Ds)[1024], float* sm){
  float mu0,rs0,mu1,rs1;
  ln_stats_g(accL+AY, EE, sm, mu0,rs0,mu1,rs1);
  for(int i=threadIdx.x;i<EE;i+=256){ float sc=sasl[i], bi=sabl[i];
    Ds[0][i]=dsi[i]    + (accL[AY+i]-mu0)*rs0*sc + bi;
    Ds[1][i]=dsi[EE+i] + (accL[AY+EE+i]-mu1)*rs1*sc + bi; }
  ln_stats_g(accL+AY2, EE, sm, mu0,rs0,mu1,rs1);
  for(int i=threadIdx.x;i<EE;i+=256){ float sc=casl[i], bi=cabl[i];
    Ds[0][i] += (accL[AY2+i]-mu0)*rs0*sc + bi;
    Ds[1][i] += (accL[AY2+EE+i]-mu1)*rs1*sc + bi; }
}

// ===== k_init: 768 ek/ev GEMM tiles (reg-prefetch double-stage) + 1 prelude block
__global__ __launch_bounds__(256)
void k_init(MegaP p){
  __shared__ float As[128][33];
  __shared__ float Bs[32][33];
  const int t=threadIdx.x, bid=blockIdx.x;
  if (bid < 768){
    int lp = bid>>5, cx = bid&31;
    int l = lp>>1, proj = lp&1;
    const float* Wt = (proj? p.cvw : p.ckw) + (size_t)l*EE*EE;
    float* outp = p.ws + (proj? OFF_EV : OFF_EK) + (size_t)l*128*EE;
    int c0 = cx*32;
    int tx=t&7, ty=t>>3;
    float acc[4][4];
    #pragma unroll
    for(int i=0;i<4;i++){ acc[i][0]=0;acc[i][1]=0;acc[i][2]=0;acc[i][3]=0; }
    float ar[16], br[4];
    #pragma unroll
    for(int j=0;j<16;j++){ int i=t+j*256; ar[j]=p.enc[(size_t)(i>>5)*EE + (i&31)]; }
    #pragma unroll
    for(int j=0;j<4;j++){ int i=t+j*256; br[j]=Wt[(size_t)(i>>5)*EE + c0 + (i&31)]; }
    for (int it=0; it<32; ++it){
      #pragma unroll
      for(int j=0;j<16;j++){ int i=t+j*256; As[i>>5][i&31]=ar[j]; }
      #pragma unroll
      for(int j=0;j<4;j++){ int i=t+j*256; Bs[i>>5][i&31]=br[j]; }
      __syncthreads();
      if (it<31){
        int k0n=(it+1)*32;
        #pragma unroll
        for(int j=0;j<16;j++){ int i=t+j*256; ar[j]=p.enc[(size_t)(i>>5)*EE + k0n + (i&31)]; }
        #pragma unroll
        for(int j=0;j<4;j++){ int i=t+j*256; br[j]=Wt[(size_t)((i>>5)+k0n)*EE + c0 + (i&31)]; }
      }
      #pragma unroll
      for (int k=0;k<32;k++){
        float b0=Bs[k][tx*4+0], b1=Bs[k][tx*4+1], b2=Bs[k][tx*4+2], b3=Bs[k][tx*4+3];
        #pragma unroll
        for (int rr=0;rr<4;rr++){
          float av = As[ty+32*rr][k];
          acc[rr][0]+=av*b0; acc[rr][1]+=av*b1; acc[rr][2]+=av*b2; acc[rr][3]+=av*b3;
        }
      }
      __syncthreads();
    }
    #pragma unroll
    for (int rr=0;rr<4;rr++)
      #pragma unroll
      for (int j=0;j<4;j++)
        outp[(size_t)(ty+32*rr)*EE + c0 + tx*4+j] = acc[rr][j];
  } else {
    // prelude: ds0 = LN(tok[pt]+pos[ti], ln_s, ln_b), both batch rows
    float* ev = &As[0][0];
    float* smv = &Bs[0][0];
    int ptv = p.pt[0], tiv = p.ti[0];
    float s0=0,q0=0,d1=0,d2=0;
    for(int i=t;i<EE;i+=256){ float v=p.tok[(size_t)ptv*EE+i]+p.pos[(size_t)tiv*EE+i]; ev[i]=v; s0+=v; q0+=v*v; }
    red4(smv,s0,q0,d1,d2);
    float mu=s0/EE, rs=rsqrtf(fmaxf(q0/EE-mu*mu,0.f)+EPS);
    float* ds0 = p.ws + OFF_DS;
    __syncthreads();
    for(int i=t;i<EE;i+=256){ float y=(ev[i]-mu)*rs*p.ln_s[i]+p.ln_b[i]; ds0[i]=y; ds0[EE+i]=y; }
  }
}

// ===== stage A: x=LN(dsi)+pre_sa_b ; q,k,v = x@{saq,sak,sav}. grid (12,64), CH=16
__global__ __launch_bounds__(256)
void k_qkv(MegaP p, int l){
  __shared__ float Xs[2][1024];
  __shared__ float sm[16];
  const int t=threadIdx.x;
  const float* dsi = p.ws + OFF_DS + (size_t)(3*l)*2048;
  float* accL = p.ws + OFF_ACC + (size_t)l*ACC_STRIDE;
  const size_t lE2=(size_t)l*EE*EE, lE=(size_t)l*EE;
  float mu0,rs0,mu1,rs1;
  ln_stats_g(dsi, EE, sm, mu0,rs0,mu1,rs1);
  for(int i=t;i<EE;i+=256){ float bi=p.pre_sa_b[lE+i];
    Xs[0][i]=(dsi[i]-mu0)*rs0+bi; Xs[1][i]=(dsi[EE+i]-mu1)*rs1+bi; }
  __syncthreads();
  int c = blockIdx.x*256 + t;            // [0,3072)
  int sel = c>>10, cc = c&1023;
  const float* W = (sel==0? p.saq : sel==1? p.sak : p.sav) + lE2;
  float* O = accL + (sel==0? AQ : sel==1? AK : AV);
  int k0 = blockIdx.y*16;
  const float* wp = W + (size_t)k0*EE + cc;
  float a0=0,a1=0;
  #pragma unroll
  for(int k=0;k<16;k++){ float w=*wp; wp+=EE; a0+=Xs[0][k0+k]*w; a1+=Xs[1][k0+k]*w; }
  atomicAdd(&O[cc],a0); atomicAdd(&O[EE+cc],a1);
}

// ===== stage C: fused self-attention + y = attn @ sao. grid 256. Writes new KV row.
__global__ __launch_bounds__(256)
void k_selfo(MegaP p, int l){
  __shared__ float Ds[2][1024];
  __shared__ float att[2][256];
  __shared__ float sm[16];
  const int t=threadIdx.x, bkid=blockIdx.x, tiv=p.ti[0];
  float* accL = p.ws + OFF_ACC + (size_t)l*ACC_STRIDE;
  const size_t lE2=(size_t)l*EE*EE;
  int cg=bkid&3, h=(bkid>>2)&15, sub=(bkid>>6)&3, hoff=h*64;
  if (t < 128){ int bb2=t>>6, c2=t&63; Ds[bb2][c2] = accL[AQ + bb2*EE + hoff + c2]*0.125f; }
  __syncthreads();
  for(int bb2=0;bb2<2;bb2++)
    for(int tt=t; tt<=tiv; tt+=256){
      const float* kr = (tt<tiv) ? (p.keys_in + (size_t)l*KVL + (size_t)bb2*KVB + (size_t)tt*EE + hoff)
                                 : (accL + AK + bb2*EE + hoff);
      float d=0;
      #pragma unroll
      for(int c2=0;c2<64;c2++) d += Ds[bb2][c2]*kr[c2];
      att[bb2][tt] = d;
    }
  __syncthreads();
  int wv=t>>6, l2=t&63;
  if (wv<2){
    float m=-3.4e38f;
    for(int tt=l2; tt<=tiv; tt+=64) m=fmaxf(m, att[wv][tt]);
    #pragma unroll
    for(int o=32;o;o>>=1) m=fmaxf(m,__shfl_xor(m,o));
    float s=0;
    for(int tt=l2; tt<=tiv; tt+=64){ float e=__expf(att[wv][tt]-m); att[wv][tt]=e; s+=e; }
    #pragma unroll
    for(int o=32;o;o>>=1) s+=__shfl_xor(s,o);
    if(l2==0) sm[8+wv]=1.f/s;
  }
  __syncthreads();
  {
    int bb2=t>>7, j=(t>>3)&15, part=t&7, colh=sub*16+j;
    float v=0;
    for(int tt=part; tt<=tiv; tt+=8){
      float vv = (tt<tiv)? p.values_in[(size_t)l*KVL + (size_t)bb2*KVB + (size_t)tt*EE + hoff + colh]
                         : accL[AV + bb2*EE + hoff + colh];
      v += att[bb2][tt]*vv;
    }
    v += __shfl_down(v,4,8); v += __shfl_down(v,2,8); v += __shfl_down(v,1,8);
    if(part==0) Ds[bb2][512+j] = v*sm[8+bb2];
  }
  __syncthreads();
  {
    int c = cg*256+t, kb = hoff + sub*16;
    const float* wp = p.sao + lE2 + (size_t)kb*EE + c;
    float a0=0,a1=0;
    #pragma unroll
    for(int j2=0;j2<16;j2++){ float w=wp[(size_t)j2*EE]; a0+=Ds[0][512+j2]*w; a1+=Ds[1][512+j2]*w; }
    atomicAdd(&accL[AY+c],a0); atomicAdd(&accL[AY+EE+c],a1);
  }
  if (cg==0 && sub==0){
    int bb2=t>>7, kv=(t>>6)&1, c2=t&63;
    float val = accL[(kv?AV:AK) + bb2*EE + hoff + c2];
    float* dst = (kv? p.values_out : p.keys_out)
               + (size_t)l*KVL + (size_t)bb2*KVB + (size_t)tiv*EE + hoff + c2;
    *dst = val;
  }
}

// ===== stage D: ds2 = dsi + LN(y)*sas+sab ; x2=LN(ds2)+pre_ca_b ; qc = x2@caq. grid (4,64), CH=16
__global__ __launch_bounds__(256)
void k_ds2caq(MegaP p, int l){
  __shared__ float Xs[2][1024];
  __shared__ float Ds[2][1024];
  __shared__ float sm[16];
  const int t=threadIdx.x;
  const float* dsi = p.ws + OFF_DS + (size_t)(3*l)*2048;
  float* accL = p.ws + OFF_ACC + (size_t)l*ACC_STRIDE;
  const size_t lE2=(size_t)l*EE*EE, lE=(size_t)l*EE;
  float mu0,rs0,mu1,rs1;
  ln_stats_g(accL+AY, EE, sm, mu0,rs0,mu1,rs1);
  for(int i=t;i<EE;i+=256){ float sc=p.sas[lE+i], bi=p.sab[lE+i];
    Ds[0][i]=dsi[i]    + (accL[AY+i]-mu0)*rs0*sc + bi;
    Ds[1][i]=dsi[EE+i] + (accL[AY+EE+i]-mu1)*rs1*sc + bi; }
  ln_stats_l(Ds, sm, mu0,rs0,mu1,rs1);
  for(int i=t;i<EE;i+=256){ float bi=p.pre_ca_b[lE+i];
    Xs[0][i]=(Ds[0][i]-mu0)*rs0+bi; Xs[1][i]=(Ds[1][i]-mu1)*rs1+bi; }
  __syncthreads();
  int c = blockIdx.x*256 + t;
  int k0 = blockIdx.y*16;
  const float* wp = p.caq + lE2 + (size_t)k0*EE + c;
  float a0=0,a1=0;
  #pragma unroll
  for(int k=0;k<16;k++){ float w=*wp; wp+=EE; a0+=Xs[0][k0+k]*w; a1+=Xs[1][k0+k]*w; }
  float* O = accL + AQC;
  atomicAdd(&O[c],a0); atomicAdd(&O[EE+c],a1);
}

// ===== stage F: fused cross-attention + y2 = attn2 @ cao. grid 256
__global__ __launch_bounds__(256)
void k_crosso(MegaP p, int l){
  __shared__ float Ds[2][1024];
  __shared__ float att[2][256];
  __shared__ float sm[16];
  const int t=threadIdx.x, bkid=blockIdx.x;
  float* accL = p.ws + OFF_ACC + (size_t)l*ACC_STRIDE;
  const size_t lE2=(size_t)l*EE*EE;
  int cg=bkid&3, h=(bkid>>2)&15, sub=(bkid>>6)&3, hoff=h*64;
  const float* ek = p.ws + OFF_EK;
  const float* ev = p.ws + OFF_EV;
  if (t < 128){ int bb2=t>>6, c2=t&63; Ds[bb2][c2] = accL[AQC + bb2*EE + hoff + c2]*0.125f; }
  __syncthreads();
  if (t < 128){
    int bb2=t>>6, tt=t&63;
    const float* kr = ek + ((size_t)l*128 + bb2*64 + tt)*EE + hoff;
    float d=0;
    #pragma unroll
    for(int c2=0;c2<64;c2++) d += Ds[bb2][c2]*kr[c2];
    int mi = bb2*64+tt;
    bool valid = (p.maski[mi]!=0) || (((const unsigned char*)p.maski)[mi]!=0);
    att[bb2][tt] = valid ? d : -3.4e38f;
  }
  __syncthreads();
  int wv=t>>6, l2=t&63;
  if (wv<2){
    float sc = att[wv][l2];
    float m = sc;
    #pragma unroll
    for(int o=32;o;o>>=1) m=fmaxf(m,__shfl_xor(m,o));
    float e = (sc>-1e37f)? __expf(sc-m) : 0.f;
    att[wv][l2]=e; float s=e;
    #pragma unroll
    for(int o=32;o;o>>=1) s+=__shfl_xor(s,o);
    if(l2==0) sm[8+wv]=1.f/s;
  }
  __syncthreads();
  {
    int bb2=t>>7, j=(t>>3)&15, part=t&7, colh=sub*16+j;
    float v=0;
    for(int tt=part; tt<64; tt+=8)
      v += att[bb2][tt]*ev[((size_t)l*128 + bb2*64 + tt)*EE + hoff + colh];
    v += __shfl_down(v,4,8); v += __shfl_down(v,2,8); v += __shfl_down(v,1,8);
    if(part==0) Ds[bb2][512+j] = v*sm[8+bb2];
  }
  __syncthreads();
  {
    int c = cg*256+t, kb = hoff + sub*16;
    const float* wp = p.cao + lE2 + (size_t)kb*EE + c;
    float a0=0,a1=0;
    #pragma unroll
    for(int j2=0;j2<16;j2++){ float w=wp[(size_t)j2*EE]; a0+=Ds[0][512+j2]*w; a1+=Ds[1][512+j2]*w; }
    atomicAdd(&accL[AY2+c],a0); atomicAdd(&accL[AY2+EE+c],a1);
  }
}

// ===== stage G: ds3 ; z=LN(ds3)+g0b ; a=z@f0, b=z@f1. grid (11,64), CH=16, float2
__global__ __launch_bounds__(256)
void k_glu01(MegaP p, int l){
  __shared__ float Xs[2][1024];
  __shared__ float Ds[2][1024];
  __shared__ float sm[16];
  const int t=threadIdx.x;
  const float* dsi = p.ws + OFF_DS + (size_t)(3*l)*2048;
  float* accL = p.ws + OFF_ACC + (size_t)l*ACC_STRIDE;
  const size_t lEG=(size_t)l*EE*GG, lE=(size_t)l*EE;
  build_ds3(dsi, accL, p.sas+lE, p.sab+lE, p.cas+lE, p.cab+lE, Ds, sm);
  float mu0,rs0,mu1,rs1;
  ln_stats_l(Ds, sm, mu0,rs0,mu1,rs1);
  for(int i=t;i<EE;i+=256){ float bi=p.g0b[lE+i];
    Xs[0][i]=(Ds[0][i]-mu0)*rs0+bi; Xs[1][i]=(Ds[1][i]-mu1)*rs1+bi; }
  __syncthreads();
  int c2 = blockIdx.x*256 + t;
  if (c2 < 2730){
    int sel = (c2>=1365), cc2 = sel? c2-1365 : c2, col = cc2*2;
    const float* W = (sel? p.f1 : p.f0) + lEG;
    float* O = accL + (sel? AB2 : AA);
    int k0 = blockIdx.y*16;
    const float2* wp = (const float2*)(W + (size_t)k0*GG + col);
    float a0=0,a1=0,b0=0,b1=0;
    #pragma unroll
    for(int k=0;k<16;k++){
      float2 w=*wp; wp+=1365;
      float x0=Xs[0][k0+k], x1=Xs[1][k0+k];
      a0+=x0*w.x; a1+=x0*w.y; b0+=x1*w.x; b1+=x1*w.y;
    }
    atomicAdd(&O[col+0],a0); atomicAdd(&O[col+1],a1);
    atomicAdd(&O[GG+col+0],b0); atomicAdd(&O[GG+col+1],b1);
  }
}

// ===== stage H: t=gelu(a)*b ; z2=LN(t)+g1b ; ds4 = ds3 + z2@f2. grid (4,86), CH=32
__global__ __launch_bounds__(256)
void k_glu2(MegaP p, int l){
  __shared__ float Xs[2][2736];
  __shared__ float Ds[2][1024];
  __shared__ float sm[16];
  const int t=threadIdx.x;
  const float* dsi = p.ws + OFF_DS + (size_t)(3*l)*2048;
  float* ds4 = p.ws + OFF_DS + (size_t)(3*l+3)*2048;
  float* accL = p.ws + OFF_ACC + (size_t)l*ACC_STRIDE;
  const size_t lGE=(size_t)l*GG*EE, lE=(size_t)l*EE, lG=(size_t)l*GG;
  const int ks = blockIdx.y;
  if (ks==0) build_ds3(dsi, accL, p.sas+lE, p.sab+lE, p.cas+lE, p.cab+lE, Ds, sm);
  float s0=0,q0=0,s1=0,q1=0;
  for(int i=t;i<GG;i+=256){
    float a0v=accL[AA+i], a1v=accL[AA+GG+i];
    float b0v=accL[AB2+i], b1v=accL[AB2+GG+i];
    float g0v=0.5f*a0v*(1.f+erff(a0v*0.70710678118654752f));
    float g1v=0.5f*a1v*(1.f+erff(a1v*0.70710678118654752f));
    float t0=g0v*b0v, t1=g1v*b1v;
    Xs[0][i]=t0; Xs[1][i]=t1;
    s0+=t0;q0+=t0*t0;s1+=t1;q1+=t1*t1;
  }
  red4(sm,s0,q0,s1,q1);
  float mu0=s0/GG, mu1=s1/GG;
  float rs0=rsqrtf(fmaxf(q0/GG-mu0*mu0,0.f)+EPS), rs1=rsqrtf(fmaxf(q1/GG-mu1*mu1,0.f)+EPS);
  for(int i=t;i<GG;i+=256){ float bi=p.g1b[lG+i];
    Xs[0][i]=(Xs[0][i]-mu0)*rs0+bi; Xs[1][i]=(Xs[1][i]-mu1)*rs1+bi; }
  __syncthreads();
  int c = blockIdx.x*256 + t;
  int k0 = ks*32, k1 = k0+32; if (k1>GG) k1=GG;
  float a0=0,b0=0;
  if (ks==0){ a0=Ds[0][c]; b0=Ds[1][c]; }
  const float* wp = p.f2 + lGE + (size_t)k0*EE + c;
  #pragma unroll 8
  for(int k=k0;k<k1;k++){ float w=*wp; wp+=EE; a0+=Xs[0][k]*w; b0+=Xs[1][k]*w; }
  atomicAdd(&ds4[c],a0); atomicAdd(&ds4[EE+c],b0);
}

// ===== final: logits = LN(ds,final_b) @ lm_head. grid (17,32), CH=32, float4
__global__ __launch_bounds__(256)
void k_lm(MegaP p){
  __shared__ float Xs[2][1024];
  __shared__ float sm[16];
  const int t=threadIdx.x;
  const float* dsf = p.ws + OFF_DS + (size_t)36*2048;
  float mu0,rs0,mu1,rs1;
  ln_stats_g(dsf, EE, sm, mu0,rs0,mu1,rs1);
  for(int i=t;i<EE;i+=256){ float bi=p.final_b[i];
    Xs[0][i]=(dsf[i]-mu0)*rs0+bi; Xs[1][i]=(dsf[EE+i]-mu1)*rs1+bi; }
  __syncthreads();
  int c4 = blockIdx.x*256 + t;
  if (c4 < 4104){
    int col = c4*4;
    int k0 = blockIdx.y*32;
    const float4* wp = (const float4*)(p.lm_w + (size_t)k0*VV + col);
    float a0=0,a1=0,a2=0,a3=0,b0=0,b1=0,b2=0,b3=0;
    #pragma unroll 8
    for(int k=0;k<32;k++){
      float4 w=*wp; wp+=4104;
      float x0=Xs[0][k0+k], x1=Xs[1][k0+k];
      a0+=x0*w.x; a1+=x0*w.y; a2+=x0*w.z; a3+=x0*w.w;
      b0+=x1*w.x; b1+=x1*w.y; b2+=x1*w.z; b3+=x1*w.w;
    }
    atomicAdd(&p.logits[col+0],a0); atomicAdd(&p.logits[col+1],a1);
    atomicAdd(&p.logits[col+2],a2); atomicAdd(&p.logits[col+3],a3);
    atomicAdd(&p.logits[VV+col+0],b0); atomicAdd(&p.logits[VV+col+1],b1);
    atomicAdd(&p.logits[VV+col+2],b2); atomicAdd(&p.logits[VV+col+3],b3);
  }
}

extern "C" void kernel_launch(void* const* d_in, const int* in_sizes, int n_in,
                              void* d_out, int out_size, void* d_ws, size_t ws_size,
                              hipStream_t stream){
  (void)in_sizes; (void)n_in; (void)out_size; (void)ws_size;
  float* out = (float*)d_out;
  float* ws = (float*)d_ws;

  MegaP P;
  P.enc        = (const float*)d_in[0];
  P.keys_in    = (const float*)d_in[1];
  P.values_in  = (const float*)d_in[2];
  P.maski      = (const int*)d_in[3];
  P.pt         = (const int*)d_in[4];
  P.ti         = (const int*)d_in[5];
  P.tok        = (const float*)d_in[6];
  P.pos        = (const float*)d_in[7];
  P.ln_s       = (const float*)d_in[8];
  P.ln_b       = (const float*)d_in[9];
  P.final_b    = (const float*)d_in[10];
  P.lm_w       = (const float*)d_in[11];
  P.pre_sa_b   = (const float*)d_in[12];
  P.saq        = (const float*)d_in[13];
  P.sak        = (const float*)d_in[14];
  P.sav        = (const float*)d_in[15];
  P.sao        = (const float*)d_in[16];
  P.sas        = (const float*)d_in[17];
  P.sab        = (const float*)d_in[18];
  P.pre_ca_b   = (const float*)d_in[19];
  P.caq        = (const float*)d_in[20];
  P.ckw        = (const float*)d_in[21];
  P.cvw        = (const float*)d_in[22];
  P.cao        = (const float*)d_in[23];
  P.cas        = (const float*)d_in[24];
  P.cab        = (const float*)d_in[25];
  P.g0b        = (const float*)d_in[26];
  P.f0         = (const float*)d_in[27];
  P.f1         = (const float*)d_in[28];
  P.g1b        = (const float*)d_in[29];
  P.f2         = (const float*)d_in[30];
  P.logits     = out;
  P.keys_out   = out + (size_t)2*VV;
  P.values_out = P.keys_out + (size_t)LAYERS*KVL;
  P.ws         = ws;

  hipMemsetAsync(ws + OFF_DS, 0, (size_t)ZERO_FLOATS*sizeof(float), stream);
  hipMemsetAsync(P.logits, 0, (size_t)2*VV*sizeof(float), stream);
  hipMemcpyAsync(P.keys_out, P.keys_in, (size_t)LAYERS*KVL*sizeof(float),
                 hipMemcpyDeviceToDevice, stream);
  hipMemcpyAsync(P.values_out, P.values_in, (size_t)LAYERS*KVL*sizeof(float),
                 hipMemcpyDeviceToDevice, stream);

  k_init<<<769,256,0,stream>>>(P);
  for (int l=0;l<LAYERS;l++){
    k_qkv   <<<dim3(12,64),256,0,stream>>>(P,l);
    k_selfo <<<256,        256,0,stream>>>(P,l);
    k_ds2caq<<<dim3(4,64), 256,0,stream>>>(P,l);
    k_crosso<<<256,        256,0,stream>>>(P,l);
    k_glu01 <<<dim3(11,64),256,0,stream>>>(P,l);
    k_glu2  <<<dim3(4,86), 256,0,stream>>>(P,l);
  }
  k_lm<<<dim3(17,32),256,0,stream>>>(P);
}

// Round 7
// 1064.855 us; speedup vs baseline: 26.1427x; 1.0898x over previous
//
#include <hip/hip_runtime.h>
#include <math.h>

#define LAYERS 12
#define EE 1024
#define GG 2730
#define VV 16416
#define EPS 1e-6f

// ---- workspace layout (float offsets) ----
#define OFF_DS 0
#define NSLOT 37
#define OFF_ACC (OFF_DS + NSLOT*2048)
#define ACC_STRIDE 28672
#define AQ 0
#define AK 2048
#define AV 4096
#define AY 6144
#define AQC 8192
#define ASC 10240
#define AOUT 12288
#define AY2 14336
#define AA 16384
#define AB2 21844
#define ACC_TOTAL (LAYERS*ACC_STRIDE)
#define ZERO_FLOATS (NSLOT*2048 + ACC_TOTAL)

#define KVL 524288   // floats per layer per cache (2 batches x 256 x 1024)
#define KVB 262144   // floats per batch

struct MegaP {
  const float* enc; const float* keys_in; const float* values_in;
  const int* maski; const int* pt; const int* ti;
  const float* tok; const float* pos; const float* ln_s; const float* ln_b;
  const float* final_b; const float* lm_w;
  const float* pre_sa_b; const float* saq; const float* sak; const float* sav;
  const float* sao; const float* sas; const float* sab;
  const float* pre_ca_b; const float* caq; const float* ckw; const float* cvw;
  const float* cao; const float* cas; const float* cab;
  const float* g0b; const float* f0; const float* f1; const float* g1b; const float* f2;
  float* logits; float* keys_out; float* values_out; float* ws;
};

__device__ __forceinline__ void red4(float* sm, float& a, float& b, float& c, float& d){
  #pragma unroll
  for(int o=32;o;o>>=1){ a+=__shfl_down(a,o); b+=__shfl_down(b,o); c+=__shfl_down(c,o); d+=__shfl_down(d,o); }
  int w=threadIdx.x>>6, l=threadIdx.x&63;
  __syncthreads();
  if(l==0){ sm[w]=a; sm[4+w]=b; sm[8+w]=c; sm[12+w]=d; }
  __syncthreads();
  a=sm[0]+sm[1]+sm[2]+sm[3]; b=sm[4]+sm[5]+sm[6]+sm[7];
  c=sm[8]+sm[9]+sm[10]+sm[11]; d=sm[12]+sm[13]+sm[14]+sm[15];
}

__device__ __forceinline__ void ln_stats_g(const float* v, int K, float* sm,
    float& mu0, float& rs0, float& mu1, float& rs1){
  float s0=0,q0=0,s1=0,q1=0;
  for(int i=threadIdx.x;i<K;i+=256){ float a=v[i], b=v[K+i]; s0+=a;q0+=a*a;s1+=b;q1+=b*b; }
  red4(sm,s0,q0,s1,q1);
  mu0=s0/K; mu1=s1/K;
  rs0=rsqrtf(fmaxf(q0/K-mu0*mu0,0.f)+EPS);
  rs1=rsqrtf(fmaxf(q1/K-mu1*mu1,0.f)+EPS);
}

__device__ __forceinline__ void ln_stats_l(float (*Ds)[1024], float* sm,
    float& mu0, float& rs0, float& mu1, float& rs1){
  float s0=0,q0=0,s1=0,q1=0;
  for(int i=threadIdx.x;i<EE;i+=256){ float a=Ds[0][i], b=Ds[1][i]; s0+=a;q0+=a*a;s1+=b;q1+=b*b; }
  red4(sm,s0,q0,s1,q1);
  mu0=s0/EE; mu1=s1/EE;
  rs0=rsqrtf(fmaxf(q0/EE-mu0*mu0,0.f)+EPS);
  rs1=rsqrtf(fmaxf(q1/EE-mu1*mu1,0.f)+EPS);
}

// ds3 = dsi + LN(AY)*sas+sab + LN(AY2)*cas+cab  -> Ds
__device__ __forceinline__ void build_ds3(const float* dsi, const float* accL,
    const float* sasl, const float* sabl, const float* casl, const float* cabl,
    float (*Ds)[1024], float* sm){
  float mu0,rs0,mu1,rs1;
  ln_stats_g(accL+AY, EE, sm, mu0,rs0,mu1,rs1);
  for(int i=threadIdx.x;i<EE;i+=256){ float sc=sasl[i], bi=sabl[i];
    Ds[0][i]=dsi[i]    + (accL[AY+i]-mu0)*rs0*sc + bi;
    Ds[1][i]=dsi[EE+i] + (accL[AY+EE+i]-mu1)*rs1*sc + bi; }
  ln_stats_g(accL+AY2, EE, sm, mu0,rs0,mu1,rs1);
  for(int i=threadIdx.x;i<EE;i+=256){ float sc=casl[i], bi=cabl[i];
    Ds[0][i] += (accL[AY2+i]-mu0)*rs0*sc + bi;
    Ds[1][i] += (accL[AY2+EE+i]-mu1)*rs1*sc + bi; }
}

// ===== prelude: ds0 = LN(tok[pt]+pos[ti], ln_s, ln_b), both batch rows. 1 block.
__global__ __launch_bounds__(256)
void k_prelude(MegaP p){
  __shared__ float ev[EE];
  __shared__ float sm[16];
  const int t=threadIdx.x;
  int ptv = p.pt[0], tiv = p.ti[0];
  float s0=0,q0=0,d1=0,d2=0;
  for(int i=t;i<EE;i+=256){ float v=p.tok[(size_t)ptv*EE+i]+p.pos[(size_t)tiv*EE+i]; ev[i]=v; s0+=v; q0+=v*v; }
  red4(sm,s0,q0,d1,d2);
  float mu=s0/EE, rs=rsqrtf(fmaxf(q0/EE-mu*mu,0.f)+EPS);
  float* ds0 = p.ws + OFF_DS;
  __syncthreads();
  for(int i=t;i<EE;i+=256){ float y=(ev[i]-mu)*rs*p.ln_s[i]+p.ln_b[i]; ds0[i]=y; ds0[EE+i]=y; }
}

// ===== stage A: x=LN(dsi)+pre_sa_b ; q,k,v = x@{saq,sak,sav}. grid (16,64)
// bx<12: GEMV CH=16 with reg-prefetch; bx>=12: 256 copy blocks for layer-l KV slice.
__global__ __launch_bounds__(256)
void k_qkv(MegaP p, int l){
  __shared__ float Xs[2][1024];
  __shared__ float sm[16];
  const int t=threadIdx.x, bx=blockIdx.x, by=blockIdx.y;
  if (bx >= 12){
    int cb = (bx-12)*64 + by;                 // [0,256)
    #pragma unroll
    for(int j=0;j<4;j++){
      int idx4 = cb*1024 + j*256 + t;         // 262144 float4 this layer
      int kv = idx4 >> 17;
      int r4 = idx4 & 131071;
      size_t off = (size_t)l*KVL + (size_t)r4*4;
      float4 v = *(const float4*)((kv? p.values_in : p.keys_in) + off);
      *(float4*)((kv? p.values_out : p.keys_out) + off) = v;
    }
    return;
  }
  const float* dsi = p.ws + OFF_DS + (size_t)(3*l)*2048;
  float* accL = p.ws + OFF_ACC + (size_t)l*ACC_STRIDE;
  const size_t lE2=(size_t)l*EE*EE, lE=(size_t)l*EE;
  int c = bx*256 + t;                         // [0,3072)
  int sel = c>>10, cc = c&1023;
  const float* W = (sel==0? p.saq : sel==1? p.sak : p.sav) + lE2;
  float* O = accL + (sel==0? AQ : sel==1? AK : AV);
  int k0 = by*16;
  const float* wp = W + (size_t)k0*EE + cc;
  float wr[16];
  #pragma unroll
  for(int k=0;k<16;k++) wr[k] = wp[(size_t)k*EE];   // issue before prologue
  float mu0,rs0,mu1,rs1;
  ln_stats_g(dsi, EE, sm, mu0,rs0,mu1,rs1);
  for(int i=t;i<EE;i+=256){ float bi=p.pre_sa_b[lE+i];
    Xs[0][i]=(dsi[i]-mu0)*rs0+bi; Xs[1][i]=(dsi[EE+i]-mu1)*rs1+bi; }
  __syncthreads();
  float a0=0,a1=0;
  #pragma unroll
  for(int k=0;k<16;k++){ a0+=Xs[0][k0+k]*wr[k]; a1+=Xs[1][k0+k]*wr[k]; }
  atomicAdd(&O[cc],a0); atomicAdd(&O[EE+cc],a1);
}

// ===== stage C: fused self-attention + y = attn @ sao. grid 256. Writes new KV row.
__global__ __launch_bounds__(256)
void k_selfo(MegaP p, int l){
  __shared__ float Ds[2][1024];
  __shared__ float att[2][256];
  __shared__ float sm[16];
  const int t=threadIdx.x, bkid=blockIdx.x, tiv=p.ti[0];
  float* accL = p.ws + OFF_ACC + (size_t)l*ACC_STRIDE;
  const size_t lE2=(size_t)l*EE*EE;
  int cg=bkid&3, h=(bkid>>2)&15, sub=(bkid>>6)&3, hoff=h*64;
  if (t < 128){ int bb2=t>>6, c2=t&63; Ds[bb2][c2] = accL[AQ + bb2*EE + hoff + c2]*0.125f; }
  __syncthreads();
  for(int bb2=0;bb2<2;bb2++)
    for(int tt=t; tt<=tiv; tt+=256){
      const float* kr = (tt<tiv) ? (p.keys_in + (size_t)l*KVL + (size_t)bb2*KVB + (size_t)tt*EE + hoff)
                                 : (accL + AK + bb2*EE + hoff);
      float d=0;
      #pragma unroll
      for(int c2=0;c2<64;c2++) d += Ds[bb2][c2]*kr[c2];
      att[bb2][tt] = d;
    }
  __syncthreads();
  int wv=t>>6, l2=t&63;
  if (wv<2){
    float m=-3.4e38f;
    for(int tt=l2; tt<=tiv; tt+=64) m=fmaxf(m, att[wv][tt]);
    #pragma unroll
    for(int o=32;o;o>>=1) m=fmaxf(m,__shfl_xor(m,o));
    float s=0;
    for(int tt=l2; tt<=tiv; tt+=64){ float e=__expf(att[wv][tt]-m); att[wv][tt]=e; s+=e; }
    #pragma unroll
    for(int o=32;o;o>>=1) s+=__shfl_xor(s,o);
    if(l2==0) sm[8+wv]=1.f/s;
  }
  __syncthreads();
  {
    int bb2=t>>7, j=(t>>3)&15, part=t&7, colh=sub*16+j;
    float v=0;
    for(int tt=part; tt<=tiv; tt+=8){
      float vv = (tt<tiv)? p.values_in[(size_t)l*KVL + (size_t)bb2*KVB + (size_t)tt*EE + hoff + colh]
                         : accL[AV + bb2*EE + hoff + colh];
      v += att[bb2][tt]*vv;
    }
    v += __shfl_down(v,4,8); v += __shfl_down(v,2,8); v += __shfl_down(v,1,8);
    if(part==0) Ds[bb2][512+j] = v*sm[8+bb2];
  }
  __syncthreads();
  {
    int c = cg*256+t, kb = hoff + sub*16;
    const float* wp = p.sao + lE2 + (size_t)kb*EE + c;
    float a0=0,a1=0;
    #pragma unroll
    for(int j2=0;j2<16;j2++){ float w=wp[(size_t)j2*EE]; a0+=Ds[0][512+j2]*w; a1+=Ds[1][512+j2]*w; }
    atomicAdd(&accL[AY+c],a0); atomicAdd(&accL[AY+EE+c],a1);
  }
  if (cg==0 && sub==0){
    int bb2=t>>7, kv=(t>>6)&1, c2=t&63;
    float val = accL[(kv?AV:AK) + bb2*EE + hoff + c2];
    float* dst = (kv? p.values_out : p.keys_out)
               + (size_t)l*KVL + (size_t)bb2*KVB + (size_t)tiv*EE + hoff + c2;
    *dst = val;
  }
}

// ===== stage D: ds2 = dsi + LN(y)*sas+sab ; x2=LN(ds2)+pre_ca_b ; qc = x2@caq. grid (4,64)
__global__ __launch_bounds__(256)
void k_ds2caq(MegaP p, int l){
  __shared__ float Xs[2][1024];
  __shared__ float Ds[2][1024];
  __shared__ float sm[16];
  const int t=threadIdx.x;
  const float* dsi = p.ws + OFF_DS + (size_t)(3*l)*2048;
  float* accL = p.ws + OFF_ACC + (size_t)l*ACC_STRIDE;
  const size_t lE2=(size_t)l*EE*EE, lE=(size_t)l*EE;
  int c = blockIdx.x*256 + t;
  int k0 = blockIdx.y*16;
  const float* wp = p.caq + lE2 + (size_t)k0*EE + c;
  float wr[16];
  #pragma unroll
  for(int k=0;k<16;k++) wr[k] = wp[(size_t)k*EE];
  float mu0,rs0,mu1,rs1;
  ln_stats_g(accL+AY, EE, sm, mu0,rs0,mu1,rs1);
  for(int i=t;i<EE;i+=256){ float sc=p.sas[lE+i], bi=p.sab[lE+i];
    Ds[0][i]=dsi[i]    + (accL[AY+i]-mu0)*rs0*sc + bi;
    Ds[1][i]=dsi[EE+i] + (accL[AY+EE+i]-mu1)*rs1*sc + bi; }
  ln_stats_l(Ds, sm, mu0,rs0,mu1,rs1);
  for(int i=t;i<EE;i+=256){ float bi=p.pre_ca_b[lE+i];
    Xs[0][i]=(Ds[0][i]-mu0)*rs0+bi; Xs[1][i]=(Ds[1][i]-mu1)*rs1+bi; }
  __syncthreads();
  float a0=0,a1=0;
  #pragma unroll
  for(int k=0;k<16;k++){ a0+=Xs[0][k0+k]*wr[k]; a1+=Xs[1][k0+k]*wr[k]; }
  float* O = accL + AQC;
  atomicAdd(&O[c],a0); atomicAdd(&O[EE+c],a1);
}

// ===== stage E1: scores via u-form. grid (32,4): block (b,h, echunk of 256).
// u_e = qc/8 . ckw[e, hblock] ; score_t += sum_e u_e * enc[b,t,e]
__global__ __launch_bounds__(256)
void k_uscore(MegaP p, int l){
  __shared__ float qs[64];
  __shared__ float us[256];
  const int t=threadIdx.x, bh=blockIdx.x, ec=blockIdx.y;
  const int b=bh>>4, h=bh&15, hoff=h*64;
  float* accL = p.ws + OFF_ACC + (size_t)l*ACC_STRIDE;
  const size_t lE2=(size_t)l*EE*EE;
  const int e = ec*256 + t;
  const float4* cp = (const float4*)(p.ckw + lE2 + (size_t)e*EE + hoff);
  float4 wr[16];
  #pragma unroll
  for(int j=0;j<16;j++) wr[j] = cp[j];        // 64 floats of ckw row e, issued early
  if (t < 64) qs[t] = accL[AQC + b*EE + hoff + t]*0.125f;
  __syncthreads();
  float u=0;
  #pragma unroll
  for(int j=0;j<16;j++){
    u += wr[j].x*qs[4*j] + wr[j].y*qs[4*j+1] + wr[j].z*qs[4*j+2] + wr[j].w*qs[4*j+3];
  }
  us[t]=u;
  __syncthreads();
  int t2=t&63, q4=t>>6;
  const float4* ep = (const float4*)(p.enc + (size_t)(b*64+t2)*EE + ec*256 + q4*64);
  float pa=0;
  #pragma unroll
  for(int j=0;j<16;j++){
    float4 e4=ep[j];
    pa += e4.x*us[q4*64+4*j] + e4.y*us[q4*64+4*j+1] + e4.z*us[q4*64+4*j+2] + e4.w*us[q4*64+4*j+3];
  }
  atomicAdd(&accL[ASC + (b*16+h)*64 + t2], pa);
}

// ===== stage E2: softmax + ctx + out = ctx@cvw. grid (32,8): (b,h) x e-range 128.
__global__ __launch_bounds__(256)
void k_ov(MegaP p, int l){
  __shared__ float att[64];
  __shared__ float ctxp[2][128];
  __shared__ float ctxs[128];
  __shared__ float smr[2];
  const int t=threadIdx.x, bh=blockIdx.x, es=blockIdx.y;
  const int b=bh>>4, h=bh&15, hoff=h*64, e0=es*128;
  float* accL = p.ws + OFF_ACC + (size_t)l*ACC_STRIDE;
  const size_t lE2=(size_t)l*EE*EE;
  const int c=t&63, part=t>>6;
  const float* vp = p.cvw + lE2 + (size_t)(e0+part*32)*EE + hoff + c;
  float wr[32];
  #pragma unroll
  for(int j=0;j<32;j++) wr[j] = vp[(size_t)j*EE];     // cvw prefetch
  if (t<64){
    float sc = accL[ASC + (b*16+h)*64 + t];
    int mi=b*64+t;
    bool valid = (p.maski[mi]!=0) || (((const unsigned char*)p.maski)[mi]!=0);
    sc = valid? sc : -3.4e38f;
    float m=sc;
    #pragma unroll
    for(int o=32;o;o>>=1) m=fmaxf(m,__shfl_xor(m,o));
    float e_ = valid? __expf(sc-m) : 0.f;
    float s=e_;
    #pragma unroll
    for(int o=32;o;o>>=1) s+=__shfl_xor(s,o);
    att[t]=e_;
    if(t==0) smr[0]=1.f/s;
  }
  __syncthreads();
  {
    int e2=t>>1, half=t&1;
    const float* ep = p.enc + (size_t)(b*64+half*32)*EE + e0+e2;
    float ca=0;
    #pragma unroll 8
    for(int tt=0;tt<32;tt++) ca += att[half*32+tt]*ep[(size_t)tt*EE];
    ctxp[half][e2]=ca;
  }
  __syncthreads();
  if (t<128) ctxs[t] = (ctxp[0][t]+ctxp[1][t])*smr[0];
  __syncthreads();
  float a=0;
  #pragma unroll
  for(int j=0;j<32;j++) a += ctxs[part*32+j]*wr[j];
  atomicAdd(&accL[AOUT + b*EE + hoff + c], a);
}

// ===== stage E3: y2 = out @ cao. grid (4,64), CH=16
__global__ __launch_bounds__(256)
void k_y2(MegaP p, int l){
  __shared__ float Xs[2][1024];
  const int t=threadIdx.x;
  float* accL = p.ws + OFF_ACC + (size_t)l*ACC_STRIDE;
  const size_t lE2=(size_t)l*EE*EE;
  int c = blockIdx.x*256 + t;
  int k0 = blockIdx.y*16;
  const float* wp = p.cao + lE2 + (size_t)k0*EE + c;
  float wr[16];
  #pragma unroll
  for(int k=0;k<16;k++) wr[k] = wp[(size_t)k*EE];
  for(int i=t;i<EE;i+=256){ Xs[0][i]=accL[AOUT+i]; Xs[1][i]=accL[AOUT+EE+i]; }
  __syncthreads();
  float a0=0,a1=0;
  #pragma unroll
  for(int k=0;k<16;k++){ a0+=Xs[0][k0+k]*wr[k]; a1+=Xs[1][k0+k]*wr[k]; }
  atomicAdd(&accL[AY2+c],a0); atomicAdd(&accL[AY2+EE+c],a1);
}

// ===== stage G: ds3 ; z=LN(ds3)+g0b ; a=z@f0, b=z@f1. grid (11,64), CH=16, float2
__global__ __launch_bounds__(256)
void k_glu01(MegaP p, int l){
  __shared__ float Xs[2][1024];
  __shared__ float Ds[2][1024];
  __shared__ float sm[16];
  const int t=threadIdx.x;
  const float* dsi = p.ws + OFF_DS + (size_t)(3*l)*2048;
  float* accL = p.ws + OFF_ACC + (size_t)l*ACC_STRIDE;
  const size_t lEG=(size_t)l*EE*GG, lE=(size_t)l*EE;
  int c2 = blockIdx.x*256 + t;
  int k0 = blockIdx.y*16;
  int sel=0, col=0;
  const float* W = nullptr;
  float2 wr[16];
  if (c2 < 2730){
    sel = (c2>=1365); int cc2 = sel? c2-1365 : c2; col = cc2*2;
    W = (sel? p.f1 : p.f0) + lEG;
    const float2* wp = (const float2*)(W + (size_t)k0*GG + col);
    #pragma unroll
    for(int k=0;k<16;k++) wr[k] = wp[(size_t)k*1365];
  }
  build_ds3(dsi, accL, p.sas+lE, p.sab+lE, p.cas+lE, p.cab+lE, Ds, sm);
  float mu0,rs0,mu1,rs1;
  ln_stats_l(Ds, sm, mu0,rs0,mu1,rs1);
  for(int i=t;i<EE;i+=256){ float bi=p.g0b[lE+i];
    Xs[0][i]=(Ds[0][i]-mu0)*rs0+bi; Xs[1][i]=(Ds[1][i]-mu1)*rs1+bi; }
  __syncthreads();
  if (c2 < 2730){
    float* O = accL + (sel? AB2 : AA);
    float a0=0,a1=0,b0=0,b1=0;
    #pragma unroll
    for(int k=0;k<16;k++){
      float x0=Xs[0][k0+k], x1=Xs[1][k0+k];
      a0+=x0*wr[k].x; a1+=x0*wr[k].y; b0+=x1*wr[k].x; b1+=x1*wr[k].y;
    }
    atomicAdd(&O[col+0],a0); atomicAdd(&O[col+1],a1);
    atomicAdd(&O[GG+col+0],b0); atomicAdd(&O[GG+col+1],b1);
  }
}

// ===== stage H: t=gelu(a)*b ; z2=LN(t)+g1b ; ds4 = ds3 + z2@f2. grid (4,86), CH=32
__global__ __launch_bounds__(256)
void k_glu2(MegaP p, int l){
  __shared__ float Xs[2][2736];
  __shared__ float Ds[2][1024];
  __shared__ float sm[16];
  const int t=threadIdx.x;
  const float* dsi = p.ws + OFF_DS + (size_t)(3*l)*2048;
  float* ds4 = p.ws + OFF_DS + (size_t)(3*l+3)*2048;
  float* accL = p.ws + OFF_ACC + (size_t)l*ACC_STRIDE;
  const size_t lGE=(size_t)l*GG*EE, lE=(size_t)l*EE, lG=(size_t)l*GG;
  const int ks = blockIdx.y;
  int c = blockIdx.x*256 + t;
  int k0 = ks*32, k1 = k0+32; if (k1>GG) k1=GG;
  const float* wp = p.f2 + lGE + (size_t)k0*EE + c;
  float wr[32];
  #pragma unroll
  for(int k=0;k<32;k++) wr[k] = (k0+k<GG) ? wp[(size_t)k*EE] : 0.f;
  if (ks==0) build_ds3(dsi, accL, p.sas+lE, p.sab+lE, p.cas+lE, p.cab+lE, Ds, sm);
  float s0=0,q0=0,s1=0,q1=0;
  for(int i=t;i<GG;i+=256){
    float a0v=accL[AA+i], a1v=accL[AA+GG+i];
    float b0v=accL[AB2+i], b1v=accL[AB2+GG+i];
    float g0v=0.5f*a0v*(1.f+erff(a0v*0.70710678118654752f));
    float g1v=0.5f*a1v*(1.f+erff(a1v*0.70710678118654752f));
    float t0=g0v*b0v, t1=g1v*b1v;
    Xs[0][i]=t0; Xs[1][i]=t1;
    s0+=t0;q0+=t0*t0;s1+=t1;q1+=t1*t1;
  }
  red4(sm,s0,q0,s1,q1);
  float mu0=s0/GG, mu1=s1/GG;
  float rs0=rsqrtf(fmaxf(q0/GG-mu0*mu0,0.f)+EPS), rs1=rsqrtf(fmaxf(q1/GG-mu1*mu1,0.f)+EPS);
  for(int i=t;i<GG;i+=256){ float bi=p.g1b[lG+i];
    Xs[0][i]=(Xs[0][i]-mu0)*rs0+bi; Xs[1][i]=(Xs[1][i]-mu1)*rs1+bi; }
  __syncthreads();
  float a0=0,b0=0;
  if (ks==0){ a0=Ds[0][c]; b0=Ds[1][c]; }
  #pragma unroll
  for(int k=0;k<32;k++){
    if (k0+k<GG){ a0+=Xs[0][k0+k]*wr[k]; b0+=Xs[1][k0+k]*wr[k]; }
  }
  atomicAdd(&ds4[c],a0); atomicAdd(&ds4[EE+c],b0);
}

// ===== final: logits = LN(ds,final_b) @ lm_head. grid (17,32), CH=32, float4
__global__ __launch_bounds__(256)
void k_lm(MegaP p){
  __shared__ float Xs[2][1024];
  __shared__ float sm[16];
  const int t=threadIdx.x;
  const float* dsf = p.ws + OFF_DS + (size_t)36*2048;
  float mu0,rs0,mu1,rs1;
  ln_stats_g(dsf, EE, sm, mu0,rs0,mu1,rs1);
  for(int i=t;i<EE;i+=256){ float bi=p.final_b[i];
    Xs[0][i]=(dsf[i]-mu0)*rs0+bi; Xs[1][i]=(dsf[EE+i]-mu1)*rs1+bi; }
  __syncthreads();
  int c4 = blockIdx.x*256 + t;
  if (c4 < 4104){
    int col = c4*4;
    int k0 = blockIdx.y*32;
    const float4* wp = (const float4*)(p.lm_w + (size_t)k0*VV + col);
    float a0=0,a1=0,a2=0,a3=0,b0=0,b1=0,b2=0,b3=0;
    #pragma unroll 8
    for(int k=0;k<32;k++){
      float4 w=*wp; wp+=4104;
      float x0=Xs[0][k0+k], x1=Xs[1][k0+k];
      a0+=x0*w.x; a1+=x0*w.y; a2+=x0*w.z; a3+=x0*w.w;
      b0+=x1*w.x; b1+=x1*w.y; b2+=x1*w.z; b3+=x1*w.w;
    }
    atomicAdd(&p.logits[col+0],a0); atomicAdd(&p.logits[col+1],a1);
    atomicAdd(&p.logits[col+2],a2); atomicAdd(&p.logits[col+3],a3);
    atomicAdd(&p.logits[VV+col+0],b0); atomicAdd(&p.logits[VV+col+1],b1);
    atomicAdd(&p.logits[VV+col+2],b2); atomicAdd(&p.logits[VV+col+3],b3);
  }
}

extern "C" void kernel_launch(void* const* d_in, const int* in_sizes, int n_in,
                              void* d_out, int out_size, void* d_ws, size_t ws_size,
                              hipStream_t stream){
  (void)in_sizes; (void)n_in; (void)out_size; (void)ws_size;
  float* out = (float*)d_out;
  float* ws = (float*)d_ws;

  MegaP P;
  P.enc        = (const float*)d_in[0];
  P.keys_in    = (const float*)d_in[1];
  P.values_in  = (const float*)d_in[2];
  P.maski      = (const int*)d_in[3];
  P.pt         = (const int*)d_in[4];
  P.ti         = (const int*)d_in[5];
  P.tok        = (const float*)d_in[6];
  P.pos        = (const float*)d_in[7];
  P.ln_s       = (const float*)d_in[8];
  P.ln_b       = (const float*)d_in[9];
  P.final_b    = (const float*)d_in[10];
  P.lm_w       = (const float*)d_in[11];
  P.pre_sa_b   = (const float*)d_in[12];
  P.saq        = (const float*)d_in[13];
  P.sak        = (const float*)d_in[14];
  P.sav        = (const float*)d_in[15];
  P.sao        = (const float*)d_in[16];
  P.sas        = (const float*)d_in[17];
  P.sab        = (const float*)d_in[18];
  P.pre_ca_b   = (const float*)d_in[19];
  P.caq        = (const float*)d_in[20];
  P.ckw        = (const float*)d_in[21];
  P.cvw        = (const float*)d_in[22];
  P.cao        = (const float*)d_in[23];
  P.cas        = (const float*)d_in[24];
  P.cab        = (const float*)d_in[25];
  P.g0b        = (const float*)d_in[26];
  P.f0         = (const float*)d_in[27];
  P.f1         = (const float*)d_in[28];
  P.g1b        = (const float*)d_in[29];
  P.f2         = (const float*)d_in[30];
  P.logits     = out;
  P.keys_out   = out + (size_t)2*VV;
  P.values_out = P.keys_out + (size_t)LAYERS*KVL;
  P.ws         = ws;

  hipMemsetAsync(ws + OFF_DS, 0, (size_t)ZERO_FLOATS*sizeof(float), stream);
  hipMemsetAsync(P.logits, 0, (size_t)2*VV*sizeof(float), stream);

  k_prelude<<<1,256,0,stream>>>(P);
  for (int l=0;l<LAYERS;l++){
    k_qkv   <<<dim3(16,64),256,0,stream>>>(P,l);
    k_selfo <<<256,        256,0,stream>>>(P,l);
    k_ds2caq<<<dim3(4,64), 256,0,stream>>>(P,l);
    k_uscore<<<dim3(32,4), 256,0,stream>>>(P,l);
    k_ov    <<<dim3(32,8), 256,0,stream>>>(P,l);
    k_y2    <<<dim3(4,64), 256,0,stream>>>(P,l);
    k_glu01 <<<dim3(11,64),256,0,stream>>>(P,l);
    k_glu2  <<<dim3(4,86), 256,0,stream>>>(P,l);
  }
  k_lm<<<dim3(17,32),256,0,stream>>>(P);
}